// Round 8
// baseline (2256.652 us; speedup 1.0000x reference)
//
#include <hip/hip_runtime.h>
#include <hip/hip_bf16.h>

#define E 256
#define H 16
#define DD 16
#define FFH 512
#define LAYERS 5
#define BB 4
#define NN 256
#define MROWS 1024  // B*N
#define NBLK 256    // mega-kernel grid

typedef __attribute__((ext_vector_type(8))) short bfrag;
typedef __attribute__((ext_vector_type(4))) float f32x4;
typedef __attribute__((ext_vector_type(8))) unsigned short us8;
typedef unsigned short u16;

__device__ __forceinline__ void bsplit(float v, u16& h, u16& l) {
    unsigned u = __float_as_uint(v);
    u16 hh = (u16)((u + 0x7fffu + ((u >> 16) & 1u)) >> 16);
    float r = v - __uint_as_float((unsigned)hh << 16);
    unsigned u2 = __float_as_uint(r);
    h = hh;
    l = (u16)((u2 + 0x7fffu + ((u2 >> 16) & 1u)) >> 16);
}

// ================= fused prep (minmax | emb | dataT | wprep) =================
union PrepS {
    float tile[32 * 33];
    struct { u16 th[64 * 40], tl[64 * 40]; } wp;
    struct { float smin[4], smax[4]; } mm;
};

__global__ __launch_bounds__(256) void k_prep(
    const float* __restrict__ data, const float* __restrict__ node_rand,
    const float* __restrict__ Wnode, const float* __restrict__ bnode,
    const float* __restrict__ Wq, const float* __restrict__ Wk, const float* __restrict__ Wv,
    const float* __restrict__ Wc, const float* __restrict__ W1, const float* __restrict__ W2,
    float* __restrict__ pmin, float* __restrict__ pmax,
    float* __restrict__ rowb, float* __restrict__ colb,
    u16* rowh, u16* rowl, u16* colh, u16* coll,
    float* __restrict__ dataT,
    u16* qh, u16* ql, u16* kh, u16* kl_, u16* vh, u16* vl,
    u16* ch, u16* cl, u16* f1h, u16* f1l, u16* f2h, u16* f2l) {
    __shared__ PrepS ps;
    int bid = blockIdx.x;
    int t = threadIdx.x;
    if (bid < 64) {
        // minmax stage-1: b = bid>>4, p = bid&15
        int b = bid >> 4, p = bid & 15;
        const float* src = data + (size_t)b * NN * NN + p * 4096;
        float lmin = 1e30f, lmax = -1e30f;
        #pragma unroll
        for (int i = 0; i < 16; i++) {
            float v = src[t + i * 256];
            lmin = fminf(lmin, v);
            lmax = fmaxf(lmax, v);
        }
        #pragma unroll
        for (int off = 32; off; off >>= 1) {
            lmin = fminf(lmin, __shfl_down(lmin, off));
            lmax = fmaxf(lmax, __shfl_down(lmax, off));
        }
        int wid = t >> 6, lane = t & 63;
        if (lane == 0) { ps.mm.smin[wid] = lmin; ps.mm.smax[wid] = lmax; }
        __syncthreads();
        if (t == 0) {
            pmin[b * 16 + p] = fminf(fminf(ps.mm.smin[0], ps.mm.smin[1]), fminf(ps.mm.smin[2], ps.mm.smin[3]));
            pmax[b * 16 + p] = fmaxf(fmaxf(ps.mm.smax[0], ps.mm.smax[1]), fmaxf(ps.mm.smax[2], ps.mm.smax[3]));
        }
    } else if (bid < 1088) {
        int idx = (bid - 64) * 256 + t;
        int bn = idx >> 8, e = idx & 255;
        float v = node_rand[bn] * Wnode[e] + bnode[e];
        rowb[idx] = v;
        colb[idx] = v;
        u16 h, l;
        bsplit(v, h, l);
        rowh[idx] = h; rowl[idx] = l;
        colh[idx] = h; coll[idx] = l;
    } else if (bid < 1344) {
        int local = bid - 1088;
        int bx = local & 7, by = (local >> 3) & 7, b = local >> 6;
        int r0 = by * 32, c0 = bx * 32;
        int tx = t & 31, ty = t >> 5;
        const float* src = data + (size_t)b * NN * NN;
        float* dst = dataT + (size_t)b * NN * NN;
        #pragma unroll
        for (int i = 0; i < 4; i++)
            ps.tile[(ty + 8 * i) * 33 + tx] = src[(size_t)(r0 + ty + 8 * i) * NN + c0 + tx];
        __syncthreads();
        #pragma unroll
        for (int i = 0; i < 4; i++)
            dst[(size_t)(c0 + ty + 8 * i) * NN + r0 + tx] = ps.tile[tx * 33 + ty + 8 * i];
    } else {
        int id = bid - 1344;
        const float* W; u16 *Dh, *Dl; int K, N, mat, s, nt;
        if (id < 1280) {
            int seg = id / 320, local = id % 320;
            mat = local >> 5; int rem = local & 31; s = rem >> 2; nt = rem & 3;
            K = 256; N = 256;
            W  = seg == 0 ? Wq : seg == 1 ? Wk : seg == 2 ? Wv : Wc;
            Dh = seg == 0 ? qh : seg == 1 ? kh : seg == 2 ? vh : ch;
            Dl = seg == 0 ? ql : seg == 1 ? kl_ : seg == 2 ? vl : cl;
        } else if (id < 1920) {
            int local = id - 1280;
            mat = local >> 6; int rem = local & 63; s = rem >> 3; nt = rem & 7;
            K = 256; N = 512; W = W1; Dh = f1h; Dl = f1l;
        } else {
            int local = id - 1920;
            mat = local >> 6; int rem = local & 63; s = rem >> 2; nt = rem & 3;
            K = 512; N = 256; W = W2; Dh = f2h; Dl = f2l;
        }
        int kk = t >> 3, nl = (t & 7) * 8;
        const float* p = W + (size_t)mat * K * N + (size_t)(s * 32 + kk) * N + nt * 64 + nl;
        float4 f0 = *(const float4*)p;
        float4 f1v = *(const float4*)(p + 4);
        float fv[8] = {f0.x, f0.y, f0.z, f0.w, f1v.x, f1v.y, f1v.z, f1v.w};
        #pragma unroll
        for (int i = 0; i < 8; i++) bsplit(fv[i], ps.wp.th[(nl + i) * 40 + kk], ps.wp.tl[(nl + i) * 40 + kk]);
        __syncthreads();
        int n = t >> 2, ko = (t & 3) * 8;
        size_t dbase = (size_t)mat * K * N + (size_t)s * N * 32 + (size_t)nt * 64 * 32
                     + (size_t)n * 32 + ko;
        *(us8*)(Dh + dbase) = *(const us8*)&ps.wp.th[n * 40 + ko];
        *(us8*)(Dl + dbase) = *(const us8*)&ps.wp.tl[n * 40 + ko];
    }
}

// k_final: stats + mix constants + barrier init
__global__ void k_final(const float* __restrict__ pmin, const float* __restrict__ pmax,
                        const float* __restrict__ Wedge, const float* __restrict__ bedge,
                        const float* __restrict__ Wmix, float* __restrict__ stats,
                        float* __restrict__ c1c0, int* __restrict__ bar) {
    int t = threadIdx.x;
    if (t < 4) {
        float mn = 1e30f, mx = -1e30f;
        #pragma unroll
        for (int p = 0; p < 16; p++) {
            mn = fminf(mn, pmin[t * 16 + p]);
            mx = fmaxf(mx, pmax[t * 16 + p]);
        }
        float rng = mx - mn;
        if (rng == 0.f) rng = 1.f;
        stats[t] = mn;
        stats[4 + t] = 1.f / rng;
    } else if (t >= 64 && t < 64 + LAYERS * 2 * H) {
        int p = t - 64;
        int lj = p >> 4, h = p & 15;
        float c1 = 0.f, c0 = 0.f;
        for (int e = 0; e < E; e++) {
            float wm = Wmix[(lj * E + e) * H + h];
            c1 += Wedge[e] * wm;
            c0 += bedge[e] * wm;
        }
        c1c0[p] = c1;
        c1c0[160 + p] = c0;
    } else if (t == 32) {
        bar[0] = 0;    // arrival counter
        bar[32] = 0;   // generation
    }
}

// ================= persistent mega-kernel =================
union SMem {
    struct { u16 AsH[32 * 40], AsL[32 * 40], BsH[64 * 40], BsL[64 * 40]; } g;
    struct { float kl[256 * 20], vl[256 * 20]; } a;
    struct { float ps[32 * 9], ps2[32 * 9]; } n;
};

__device__ __forceinline__ void gridbar(int* __restrict__ bar) {
    __syncthreads();
    __threadfence();
    if (threadIdx.x == 0) {
        int* cnt = bar;
        int* gen = bar + 32;
        int g = __hip_atomic_load(gen, __ATOMIC_RELAXED, __HIP_MEMORY_SCOPE_AGENT);
        int arrived = __hip_atomic_fetch_add(cnt, 1, __ATOMIC_ACQ_REL, __HIP_MEMORY_SCOPE_AGENT);
        if (arrived == NBLK - 1) {
            __hip_atomic_store(cnt, 0, __ATOMIC_RELAXED, __HIP_MEMORY_SCOPE_AGENT);
            __hip_atomic_fetch_add(gen, 1, __ATOMIC_RELEASE, __HIP_MEMORY_SCOPE_AGENT);
        } else {
            while (__hip_atomic_load(gen, __ATOMIC_RELAXED, __HIP_MEMORY_SCOPE_AGENT) == g)
                __builtin_amdgcn_s_sleep(2);
        }
    }
    __threadfence();
    __syncthreads();
}

// 32x64 GEMM tile, 3-term bf16 split. A hi/lo plain [1024][K]; B hi/lo packed.
__device__ __forceinline__ void gemm32(SMem& sm,
                                       const u16* __restrict__ Ah, const u16* __restrict__ Al,
                                       const u16* __restrict__ Bh, const u16* __restrict__ Bl,
                                       const float* __restrict__ bias, const float* __restrict__ R,
                                       float* __restrict__ Cf, u16* __restrict__ Ch, u16* __restrict__ Cl,
                                       int K, int Ncols, int relu, int mBase, int nBase) {
    int t = threadIdx.x;
    int lane = t & 63, wave = t >> 6;
    int quad = lane >> 4, l16 = lane & 15;
    int r16 = (wave & 1) * 16, c32 = (wave >> 1) * 32;
    f32x4 acc0 = {0.f, 0.f, 0.f, 0.f}, acc1 = acc0;
    int nslab = K >> 5;
    int arow = t >> 2, ako = (t & 3) * 8;   // t<128: A staging
    int bn = t >> 2, bko = (t & 3) * 8;     // B staging (all threads)
    for (int s = 0; s < nslab; s++) {
        us8 vbh = *(const us8*)(Bh + ((size_t)s * Ncols + nBase) * 32 + t * 8);
        us8 vbl = *(const us8*)(Bl + ((size_t)s * Ncols + nBase) * 32 + t * 8);
        us8 vah, val;
        if (t < 128) {
            vah = *(const us8*)(Ah + (size_t)(mBase + arow) * K + s * 32 + ako);
            val = *(const us8*)(Al + (size_t)(mBase + arow) * K + s * 32 + ako);
        }
        __syncthreads();
        *(us8*)&sm.g.BsH[bn * 40 + bko] = vbh;
        *(us8*)&sm.g.BsL[bn * 40 + bko] = vbl;
        if (t < 128) {
            *(us8*)&sm.g.AsH[arow * 40 + ako] = vah;
            *(us8*)&sm.g.AsL[arow * 40 + ako] = val;
        }
        __syncthreads();
        bfrag a_h = *(const bfrag*)&sm.g.AsH[(r16 + l16) * 40 + quad * 8];
        bfrag a_l = *(const bfrag*)&sm.g.AsL[(r16 + l16) * 40 + quad * 8];
        bfrag b_h0 = *(const bfrag*)&sm.g.BsH[(c32 + l16) * 40 + quad * 8];
        bfrag b_h1 = *(const bfrag*)&sm.g.BsH[(c32 + 16 + l16) * 40 + quad * 8];
        bfrag b_l0 = *(const bfrag*)&sm.g.BsL[(c32 + l16) * 40 + quad * 8];
        bfrag b_l1 = *(const bfrag*)&sm.g.BsL[(c32 + 16 + l16) * 40 + quad * 8];
        acc0 = __builtin_amdgcn_mfma_f32_16x16x32_bf16(a_h, b_h0, acc0, 0, 0, 0);
        acc1 = __builtin_amdgcn_mfma_f32_16x16x32_bf16(a_h, b_h1, acc1, 0, 0, 0);
        acc0 = __builtin_amdgcn_mfma_f32_16x16x32_bf16(a_h, b_l0, acc0, 0, 0, 0);
        acc1 = __builtin_amdgcn_mfma_f32_16x16x32_bf16(a_h, b_l1, acc1, 0, 0, 0);
        acc0 = __builtin_amdgcn_mfma_f32_16x16x32_bf16(a_l, b_h0, acc0, 0, 0, 0);
        acc1 = __builtin_amdgcn_mfma_f32_16x16x32_bf16(a_l, b_h1, acc1, 0, 0, 0);
    }
    int col0 = nBase + c32 + l16;
    int col1 = col0 + 16;
    float bia0 = bias ? bias[col0] : 0.f;
    float bia1 = bias ? bias[col1] : 0.f;
    #pragma unroll
    for (int r = 0; r < 4; r++) {
        int row = mBase + r16 + quad * 4 + r;
        float v0 = acc0[r] + bia0, v1 = acc1[r] + bia1;
        if (R) {
            v0 += R[(size_t)row * Ncols + col0];
            v1 += R[(size_t)row * Ncols + col1];
        }
        if (relu) { v0 = fmaxf(v0, 0.f); v1 = fmaxf(v1, 0.f); }
        if (Cf) {
            Cf[(size_t)row * Ncols + col0] = v0;
            Cf[(size_t)row * Ncols + col1] = v1;
        } else {
            u16 h, l;
            bsplit(v0, h, l); Ch[(size_t)row * Ncols + col0] = h; Cl[(size_t)row * Ncols + col0] = l;
            bsplit(v1, h, l); Ch[(size_t)row * Ncols + col1] = h; Cl[(size_t)row * Ncols + col1] = l;
        }
    }
}

struct MegaArgs {
    const float *data, *dataT, *stats, *c1c0;
    const float *bcomb, *b1, *b2, *n1w, *n1b, *n2w, *n2b;
    const u16 *WqTh, *WqTl, *WkTh, *WkTl, *WvTh, *WvTl, *WcTh, *WcTl, *W1Th, *W1Tl, *W2Th, *W2Tl;
    float *row, *col, *q0, *q1, *k0, *k1, *v0, *v1;
    u16 *rowh, *rowl, *colh, *coll;
    u16 *atth0, *attl0, *atth1, *attl1;
    u16 *o1h0, *o1l0, *o1h1, *o1l1;
    u16 *ffhh0, *ffhl0, *ffhh1, *ffhl1;
    float* out;
    int* bar;
};

__global__ __launch_bounds__(256) void k_layers(MegaArgs A) {
    __shared__ SMem sm;
    int bid = blockIdx.x;
    int t = threadIdx.x;

    for (int l = 0; l < LAYERS; l++) {
        // ---- stage 0: QKV (768 units: z6 x m32 x n4) ----
        for (int i = 0; i < 3; i++) {
            int u = bid + 256 * i;
            int z = u >> 7, rem = u & 127;
            int my = rem & 31, nx = rem >> 5;
            int j = z / 3, w = z % 3;
            const u16* Ah = (w == 0) ? (j ? A.colh : A.rowh) : (j ? A.rowh : A.colh);
            const u16* Al = (w == 0) ? (j ? A.coll : A.rowl) : (j ? A.rowl : A.coll);
            const u16* Bh = (w == 0 ? A.WqTh : (w == 1 ? A.WkTh : A.WvTh)) + (size_t)(l * 2 + j) * E * E;
            const u16* Bl = (w == 0 ? A.WqTl : (w == 1 ? A.WkTl : A.WvTl)) + (size_t)(l * 2 + j) * E * E;
            float* Cf = w == 0 ? (j ? A.q1 : A.q0) : w == 1 ? (j ? A.k1 : A.k0) : (j ? A.v1 : A.v0);
            gemm32(sm, Ah, Al, Bh, Bl, nullptr, nullptr, Cf, nullptr, nullptr,
                   E, E, 0, my * 32, nx * 64);
        }
        gridbar(A.bar);

        // ---- stage 1: attention (256 units: b4 x h16 x nh2 x j2) ----
        {
            int j = bid & 1, nh = (bid >> 1) & 1, h = (bid >> 2) & 15, b = bid >> 6;
            const float* q = j ? A.q1 : A.q0;
            const float* k = j ? A.k1 : A.k0;
            const float* v = j ? A.v1 : A.v0;
            float mn = A.stats[b], inv = A.stats[4 + b];
            float c1 = A.c1c0[(l * 2 + j) * 16 + h];
            float c0 = A.c1c0[160 + (l * 2 + j) * 16 + h];
            float c1p = inv * c1;
            float c0p = c0 - mn * c1p;
            {
                int c = t & 3, mb = t >> 2;
                #pragma unroll
                for (int it = 0; it < 4; it++) {
                    int m = mb + 64 * it;
                    const float* kp = k + ((size_t)(b * NN + m) * E) + h * DD + c * 4;
                    const float* vp = v + ((size_t)(b * NN + m) * E) + h * DD + c * 4;
                    *(float4*)&sm.a.kl[m * 20 + c * 4] = *(const float4*)kp;
                    *(float4*)&sm.a.vl[m * 20 + c * 4] = *(const float4*)vp;
                }
            }
            __syncthreads();
            int lane = t & 63, w = t >> 6;
            int r = lane >> 3, ml = lane & 7;
            const float* edgebase = (j ? A.dataT : A.data) + (size_t)b * NN * NN;
            for (int pass = 0; pass < 4; pass++) {
                int n = nh * 128 + pass * 32 + w * 8 + r;
                float qr[16];
                const float* qp = q + ((size_t)(b * NN + n) * E) + h * DD;
                #pragma unroll
                for (int d4 = 0; d4 < 4; d4++) {
                    float4 q4 = *(const float4*)(qp + d4 * 4);
                    qr[d4 * 4 + 0] = q4.x; qr[d4 * 4 + 1] = q4.y;
                    qr[d4 * 4 + 2] = q4.z; qr[d4 * 4 + 3] = q4.w;
                }
                const float* pedge = edgebase + (size_t)n * NN;
                float sum = 0.f;
                float acc[16] = {};
                for (int i = 0; i < 32; i++) {
                    int m = ml + 8 * i;
                    float4 ka = *(const float4*)&sm.a.kl[m * 20 + 0];
                    float4 kb = *(const float4*)&sm.a.kl[m * 20 + 4];
                    float4 kc = *(const float4*)&sm.a.kl[m * 20 + 8];
                    float4 kd = *(const float4*)&sm.a.kl[m * 20 + 12];
                    float s0 = qr[0] * ka.x + qr[1] * ka.y + qr[2] * ka.z + qr[3] * ka.w;
                    float s1 = qr[4] * kb.x + qr[5] * kb.y + qr[6] * kb.z + qr[7] * kb.w;
                    float s2 = qr[8] * kc.x + qr[9] * kc.y + qr[10] * kc.z + qr[11] * kc.w;
                    float s3 = qr[12] * kd.x + qr[13] * kd.y + qr[14] * kd.z + qr[15] * kd.w;
                    float s = ((s0 + s1) + (s2 + s3)) * 0.25f + pedge[m] * c1p + c0p;
                    float e = __expf(s);
                    sum += e;
                    float4 va = *(const float4*)&sm.a.vl[m * 20 + 0];
                    float4 vb = *(const float4*)&sm.a.vl[m * 20 + 4];
                    float4 vc = *(const float4*)&sm.a.vl[m * 20 + 8];
                    float4 vd = *(const float4*)&sm.a.vl[m * 20 + 12];
                    acc[0] += e * va.x;  acc[1] += e * va.y;  acc[2] += e * va.z;  acc[3] += e * va.w;
                    acc[4] += e * vb.x;  acc[5] += e * vb.y;  acc[6] += e * vb.z;  acc[7] += e * vb.w;
                    acc[8] += e * vc.x;  acc[9] += e * vc.y;  acc[10] += e * vc.z; acc[11] += e * vc.w;
                    acc[12] += e * vd.x; acc[13] += e * vd.y; acc[14] += e * vd.z; acc[15] += e * vd.w;
                }
                #pragma unroll
                for (int mask = 1; mask <= 4; mask <<= 1) {
                    sum += __shfl_xor(sum, mask);
                    #pragma unroll
                    for (int d = 0; d < 16; d++) acc[d] += __shfl_xor(acc[d], mask);
                }
                if (ml == 0) {
                    float invs = 1.f / sum;
                    u16 hh[16], ll[16];
                    #pragma unroll
                    for (int d = 0; d < 16; d++) bsplit(acc[d] * invs, hh[d], ll[d]);
                    size_t base = ((size_t)(b * NN + n) * E) + h * DD;
                    u16* oh = (j ? A.atth1 : A.atth0) + base;
                    u16* ol = (j ? A.attl1 : A.attl0) + base;
                    *(us8*)oh = *(const us8*)&hh[0];
                    *(us8*)(oh + 8) = *(const us8*)&hh[8];
                    *(us8*)ol = *(const us8*)&ll[0];
                    *(us8*)(ol + 8) = *(const us8*)&ll[8];
                }
            }
        }
        gridbar(A.bar);

        // ---- stage 2: comb (256 units: m32 x n4 x j2) -> y (q alias) fp32 ----
        {
            int my = bid & 31, nx = (bid >> 5) & 3, j = bid >> 7;
            gemm32(sm, j ? A.atth1 : A.atth0, j ? A.attl1 : A.attl0,
                   A.WcTh + (size_t)(l * 2 + j) * E * E, A.WcTl + (size_t)(l * 2 + j) * E * E,
                   A.bcomb + (size_t)(l * 2 + j) * E, j ? A.col : A.row,
                   j ? A.q1 : A.q0, nullptr, nullptr, E, E, 0, my * 32, nx * 64);
        }
        gridbar(A.bar);

        // ---- stage 3: IN1 (256 units) y(q) -> o1f(k) + o1 hi/lo ----
        {
            int b = bid >> 6, j = (bid >> 5) & 1, ec = (bid & 31) * 8;
            const float* Y = (j ? A.q1 : A.q0) + (size_t)b * NN * E;
            float* O = (j ? A.k1 : A.k0) + (size_t)b * NN * E;
            u16* Oh = (j ? A.o1h1 : A.o1h0) + (size_t)b * NN * E;
            u16* Ol = (j ? A.o1l1 : A.o1l0) + (size_t)b * NN * E;
            const float* w = A.n1w + (size_t)(l * 2 + j) * E;
            const float* bb = A.n1b + (size_t)(l * 2 + j) * E;
            int et = t & 7, n0 = t >> 3;
            int e = ec + et;
            float vals[8];
            float s = 0.f, s2 = 0.f;
            #pragma unroll
            for (int kk = 0; kk < 8; kk++) {
                float v = Y[(size_t)(n0 + 32 * kk) * E + e];
                vals[kk] = v;
                s += v;
                s2 += v * v;
            }
            __syncthreads();
            sm.n.ps[n0 * 9 + et] = s;
            sm.n.ps2[n0 * 9 + et] = s2;
            __syncthreads();
            float st = 0.f, st2 = 0.f;
            #pragma unroll
            for (int kk = 0; kk < 32; kk++) { st += sm.n.ps[kk * 9 + et]; st2 += sm.n.ps2[kk * 9 + et]; }
            float mu = st * (1.f / NN);
            float var = fmaxf(st2 * (1.f / NN) - mu * mu, 0.f);
            float scale = w[e] * rsqrtf(var + 1e-5f);
            float shift = bb[e] - mu * scale;
            #pragma unroll
            for (int kk = 0; kk < 8; kk++) {
                float vv = vals[kk] * scale + shift;
                size_t idx = (size_t)(n0 + 32 * kk) * E + e;
                O[idx] = vv;
                u16 hh, ll;
                bsplit(vv, hh, ll);
                Oh[idx] = hh;
                Ol[idx] = ll;
            }
        }
        gridbar(A.bar);

        // ---- stage 4: FF1 (512 units: m32 x n8 x j2), relu, out hi/lo ----
        for (int i = 0; i < 2; i++) {
            int u = bid + 256 * i;
            int my = u & 31, nx = (u >> 5) & 7, j = u >> 8;
            gemm32(sm, j ? A.o1h1 : A.o1h0, j ? A.o1l1 : A.o1l0,
                   A.W1Th + (size_t)(l * 2 + j) * E * FFH, A.W1Tl + (size_t)(l * 2 + j) * E * FFH,
                   A.b1 + (size_t)(l * 2 + j) * FFH, nullptr,
                   nullptr, j ? A.ffhh1 : A.ffhh0, j ? A.ffhl1 : A.ffhl0,
                   E, FFH, 1, my * 32, nx * 64);
        }
        gridbar(A.bar);

        // ---- stage 5: FF2 (256 units), K=512, +o1f residual -> y2 (q alias) ----
        {
            int my = bid & 31, nx = (bid >> 5) & 3, j = bid >> 7;
            gemm32(sm, j ? A.ffhh1 : A.ffhh0, j ? A.ffhl1 : A.ffhl0,
                   A.W2Th + (size_t)(l * 2 + j) * FFH * E, A.W2Tl + (size_t)(l * 2 + j) * FFH * E,
                   A.b2 + (size_t)(l * 2 + j) * E, j ? A.k1 : A.k0,
                   j ? A.q1 : A.q0, nullptr, nullptr, FFH, E, 0, my * 32, nx * 64);
        }
        gridbar(A.bar);

        // ---- stage 6: IN2 (256 units) y2(q) -> row/col fp32 + hi/lo (+ final out) ----
        {
            int b = bid >> 6, j = (bid >> 5) & 1, ec = (bid & 31) * 8;
            const float* Y = (j ? A.q1 : A.q0) + (size_t)b * NN * E;
            float* O = (j ? A.col : A.row) + (size_t)b * NN * E;
            u16* Oh = (j ? A.colh : A.rowh) + (size_t)b * NN * E;
            u16* Ol = (j ? A.coll : A.rowl) + (size_t)b * NN * E;
            const float* w = A.n2w + (size_t)(l * 2 + j) * E;
            const float* bb = A.n2b + (size_t)(l * 2 + j) * E;
            float* fout = (l == LAYERS - 1) ? A.out + (size_t)j * (BB * NN * E) + (size_t)b * NN * E : nullptr;
            int et = t & 7, n0 = t >> 3;
            int e = ec + et;
            float vals[8];
            float s = 0.f, s2 = 0.f;
            #pragma unroll
            for (int kk = 0; kk < 8; kk++) {
                float v = Y[(size_t)(n0 + 32 * kk) * E + e];
                vals[kk] = v;
                s += v;
                s2 += v * v;
            }
            __syncthreads();
            sm.n.ps[n0 * 9 + et] = s;
            sm.n.ps2[n0 * 9 + et] = s2;
            __syncthreads();
            float st = 0.f, st2 = 0.f;
            #pragma unroll
            for (int kk = 0; kk < 32; kk++) { st += sm.n.ps[kk * 9 + et]; st2 += sm.n.ps2[kk * 9 + et]; }
            float mu = st * (1.f / NN);
            float var = fmaxf(st2 * (1.f / NN) - mu * mu, 0.f);
            float scale = w[e] * rsqrtf(var + 1e-5f);
            float shift = bb[e] - mu * scale;
            #pragma unroll
            for (int kk = 0; kk < 8; kk++) {
                float vv = vals[kk] * scale + shift;
                size_t idx = (size_t)(n0 + 32 * kk) * E + e;
                O[idx] = vv;
                u16 hh, ll;
                bsplit(vv, hh, ll);
                Oh[idx] = hh;
                Ol[idx] = ll;
                if (fout) fout[idx] = vv;
            }
        }
        if (l < LAYERS - 1) gridbar(A.bar);
    }
}

// ---------------- host ----------------

extern "C" void kernel_launch(void* const* d_in, const int* in_sizes, int n_in,
                              void* d_out, int out_size, void* d_ws, size_t ws_size,
                              hipStream_t stream) {
    const float* data      = (const float*)d_in[0];
    const float* node_rand = (const float*)d_in[1];
    const float* Wnode     = (const float*)d_in[2];
    const float* bnode     = (const float*)d_in[3];
    const float* Wedge     = (const float*)d_in[4];
    const float* bedge     = (const float*)d_in[5];
    const float* Wq        = (const float*)d_in[6];
    const float* Wk        = (const float*)d_in[7];
    const float* Wv        = (const float*)d_in[8];
    const float* Wcomb     = (const float*)d_in[9];
    const float* bcomb     = (const float*)d_in[10];
    const float* n1w       = (const float*)d_in[11];
    const float* n1b       = (const float*)d_in[12];
    const float* W1        = (const float*)d_in[13];
    const float* b1        = (const float*)d_in[14];
    const float* W2        = (const float*)d_in[15];
    const float* b2        = (const float*)d_in[16];
    const float* n2w       = (const float*)d_in[17];
    const float* n2b       = (const float*)d_in[18];
    const float* Wmix      = (const float*)d_in[19];
    float* out = (float*)d_out;

    float* ws = (float*)d_ws;
    const size_t T = (size_t)MROWS * E;      // 262144
    const size_t TF = (size_t)MROWS * FFH;   // 524288
    float* dataT = ws + 0 * T;
    float* row   = ws + 1 * T;
    float* col   = ws + 2 * T;
    float* q0    = ws + 3 * T;
    float* q1    = ws + 4 * T;
    float* k0    = ws + 5 * T;
    float* k1    = ws + 6 * T;
    float* v0    = ws + 7 * T;
    float* v1    = ws + 8 * T;
    float* stats = ws + 9 * T;
    float* pmin  = stats + 8;
    float* pmax  = pmin + 64;
    float* c1c0  = pmax + 64;
    int*   bar   = (int*)(ws + 9 * T + 512);   // bar[0]=cnt, bar[32]=gen
    u16* us = (u16*)(ws + 9 * T + 1024);
    auto nxt = [&](size_t n) { u16* p = us; us += n; return p; };
    u16* rowh = nxt(T);  u16* rowl = nxt(T);
    u16* colh = nxt(T);  u16* coll = nxt(T);
    u16* atth0 = nxt(T); u16* attl0 = nxt(T);
    u16* atth1 = nxt(T); u16* attl1 = nxt(T);
    u16* o1h0 = nxt(T);  u16* o1l0 = nxt(T);
    u16* o1h1 = nxt(T);  u16* o1l1 = nxt(T);
    u16* ffhh0 = nxt(TF); u16* ffhl0 = nxt(TF);
    u16* ffhh1 = nxt(TF); u16* ffhl1 = nxt(TF);
    const size_t EE10 = (size_t)10 * E * E;
    const size_t EF10 = (size_t)10 * E * FFH;
    u16* WqTh = nxt(EE10); u16* WqTl = nxt(EE10);
    u16* WkTh = nxt(EE10); u16* WkTl = nxt(EE10);
    u16* WvTh = nxt(EE10); u16* WvTl = nxt(EE10);
    u16* WcTh = nxt(EE10); u16* WcTl = nxt(EE10);
    u16* W1Th = nxt(EF10); u16* W1Tl = nxt(EF10);
    u16* W2Th = nxt(EF10); u16* W2Tl = nxt(EF10);

    k_prep<<<3904, 256, 0, stream>>>(data, node_rand, Wnode, bnode,
                                     Wq, Wk, Wv, Wcomb, W1, W2,
                                     pmin, pmax, row, col, rowh, rowl, colh, coll, dataT,
                                     WqTh, WqTl, WkTh, WkTl, WvTh, WvTl,
                                     WcTh, WcTl, W1Th, W1Tl, W2Th, W2Tl);
    k_final<<<1, 256, 0, stream>>>(pmin, pmax, Wedge, bedge, Wmix, stats, c1c0, bar);

    MegaArgs MA;
    MA.data = data; MA.dataT = dataT; MA.stats = stats; MA.c1c0 = c1c0;
    MA.bcomb = bcomb; MA.b1 = b1; MA.b2 = b2;
    MA.n1w = n1w; MA.n1b = n1b; MA.n2w = n2w; MA.n2b = n2b;
    MA.WqTh = WqTh; MA.WqTl = WqTl; MA.WkTh = WkTh; MA.WkTl = WkTl;
    MA.WvTh = WvTh; MA.WvTl = WvTl; MA.WcTh = WcTh; MA.WcTl = WcTl;
    MA.W1Th = W1Th; MA.W1Tl = W1Tl; MA.W2Th = W2Th; MA.W2Tl = W2Tl;
    MA.row = row; MA.col = col; MA.q0 = q0; MA.q1 = q1;
    MA.k0 = k0; MA.k1 = k1; MA.v0 = v0; MA.v1 = v1;
    MA.rowh = rowh; MA.rowl = rowl; MA.colh = colh; MA.coll = coll;
    MA.atth0 = atth0; MA.attl0 = attl0; MA.atth1 = atth1; MA.attl1 = attl1;
    MA.o1h0 = o1h0; MA.o1l0 = o1l0; MA.o1h1 = o1h1; MA.o1l1 = o1l1;
    MA.ffhh0 = ffhh0; MA.ffhl0 = ffhl0; MA.ffhh1 = ffhh1; MA.ffhl1 = ffhl1;
    MA.out = out; MA.bar = bar;

    k_layers<<<NBLK, 256, 0, stream>>>(MA);
}

// Round 9
// 699.760 us; speedup vs baseline: 3.2249x; 3.2249x over previous
//
#include <hip/hip_runtime.h>
#include <hip/hip_bf16.h>

#define E 256
#define H 16
#define DD 16
#define FFH 512
#define LAYERS 5
#define BB 4
#define NN 256
#define MROWS 1024  // B*N

typedef __attribute__((ext_vector_type(8))) short bfrag;
typedef __attribute__((ext_vector_type(4))) float f32x4;
typedef __attribute__((ext_vector_type(8))) unsigned short us8;
typedef unsigned short u16;

__device__ __forceinline__ void bsplit(float v, u16& h, u16& l) {
    unsigned u = __float_as_uint(v);
    u16 hh = (u16)((u + 0x7fffu + ((u >> 16) & 1u)) >> 16);
    float r = v - __uint_as_float((unsigned)hh << 16);
    unsigned u2 = __float_as_uint(r);
    h = hh;
    l = (u16)((u2 + 0x7fffu + ((u2 >> 16) & 1u)) >> 16);
}

// ---- LDS-free wave GEMM: A hi/lo row-major [1024][K]; B hi/lo packed [kslab][col][32].
// Wave computes MT x NT tiles of 16x16 at (mBase, nBase). Bit-identical MFMA order to R7.
template<int MT, int NT>
__device__ __forceinline__ void wave_gemm(const u16* __restrict__ Ah, const u16* __restrict__ Al,
                                          const u16* __restrict__ Bh, const u16* __restrict__ Bl,
                                          int mBase, int nBase, int K, int Ncols,
                                          f32x4 acc[MT][NT]) {
    int lane = threadIdx.x & 63;
    int quad = lane >> 4, l16 = lane & 15;
    const u16* aph = Ah + (size_t)(mBase + l16) * K + quad * 8;
    const u16* apl = Al + (size_t)(mBase + l16) * K + quad * 8;
    const u16* bph = Bh + (size_t)(nBase + l16) * 32 + quad * 8;
    const u16* bpl = Bl + (size_t)(nBase + l16) * 32 + quad * 8;
    int nslab = K >> 5;
    for (int s = 0; s < nslab; s++) {
        bfrag ah[MT], al[MT], bh[NT], bl[NT];
        #pragma unroll
        for (int mt = 0; mt < MT; mt++) {
            ah[mt] = *(const bfrag*)(aph + (size_t)(mt * 16) * K + s * 32);
            al[mt] = *(const bfrag*)(apl + (size_t)(mt * 16) * K + s * 32);
        }
        #pragma unroll
        for (int nt = 0; nt < NT; nt++) {
            bh[nt] = *(const bfrag*)(bph + ((size_t)s * Ncols + nt * 16) * 32);
            bl[nt] = *(const bfrag*)(bpl + ((size_t)s * Ncols + nt * 16) * 32);
        }
        #pragma unroll
        for (int mt = 0; mt < MT; mt++)
            #pragma unroll
            for (int nt = 0; nt < NT; nt++) {
                acc[mt][nt] = __builtin_amdgcn_mfma_f32_16x16x32_bf16(ah[mt], bh[nt], acc[mt][nt], 0, 0, 0);
                acc[mt][nt] = __builtin_amdgcn_mfma_f32_16x16x32_bf16(ah[mt], bl[nt], acc[mt][nt], 0, 0, 0);
                acc[mt][nt] = __builtin_amdgcn_mfma_f32_16x16x32_bf16(al[mt], bh[nt], acc[mt][nt], 0, 0, 0);
            }
    }
}

// ================= fused prep (minmax | emb | dataT | wprep) =================
union PrepS {
    float tile[32 * 33];
    struct { u16 th[64 * 40], tl[64 * 40]; } wp;
    struct { float smin[4], smax[4]; } mm;
};

__global__ __launch_bounds__(256) void k_prep(
    const float* __restrict__ data, const float* __restrict__ node_rand,
    const float* __restrict__ Wnode, const float* __restrict__ bnode,
    const float* __restrict__ Wq, const float* __restrict__ Wk, const float* __restrict__ Wv,
    const float* __restrict__ Wc, const float* __restrict__ W1, const float* __restrict__ W2,
    float* __restrict__ pmin, float* __restrict__ pmax,
    float* __restrict__ rowb, float* __restrict__ colb,
    u16* rowh, u16* rowl, u16* colh, u16* coll,
    float* __restrict__ dataT,
    u16* qh, u16* ql, u16* kh, u16* kl_, u16* vh, u16* vl,
    u16* ch, u16* cl, u16* f1h, u16* f1l, u16* f2h, u16* f2l) {
    __shared__ PrepS ps;
    int bid = blockIdx.x;
    int t = threadIdx.x;
    if (bid < 64) {
        int b = bid >> 4, p = bid & 15;
        const float* src = data + (size_t)b * NN * NN + p * 4096;
        float lmin = 1e30f, lmax = -1e30f;
        #pragma unroll
        for (int i = 0; i < 16; i++) {
            float v = src[t + i * 256];
            lmin = fminf(lmin, v);
            lmax = fmaxf(lmax, v);
        }
        #pragma unroll
        for (int off = 32; off; off >>= 1) {
            lmin = fminf(lmin, __shfl_down(lmin, off));
            lmax = fmaxf(lmax, __shfl_down(lmax, off));
        }
        int wid = t >> 6, lane = t & 63;
        if (lane == 0) { ps.mm.smin[wid] = lmin; ps.mm.smax[wid] = lmax; }
        __syncthreads();
        if (t == 0) {
            pmin[b * 16 + p] = fminf(fminf(ps.mm.smin[0], ps.mm.smin[1]), fminf(ps.mm.smin[2], ps.mm.smin[3]));
            pmax[b * 16 + p] = fmaxf(fmaxf(ps.mm.smax[0], ps.mm.smax[1]), fmaxf(ps.mm.smax[2], ps.mm.smax[3]));
        }
    } else if (bid < 1088) {
        int idx = (bid - 64) * 256 + t;
        int bn = idx >> 8, e = idx & 255;
        float v = node_rand[bn] * Wnode[e] + bnode[e];
        rowb[idx] = v;
        colb[idx] = v;
        u16 h, l;
        bsplit(v, h, l);
        rowh[idx] = h; rowl[idx] = l;
        colh[idx] = h; coll[idx] = l;
    } else if (bid < 1344) {
        int local = bid - 1088;
        int bx = local & 7, by = (local >> 3) & 7, b = local >> 6;
        int r0 = by * 32, c0 = bx * 32;
        int tx = t & 31, ty = t >> 5;
        const float* src = data + (size_t)b * NN * NN;
        float* dst = dataT + (size_t)b * NN * NN;
        #pragma unroll
        for (int i = 0; i < 4; i++)
            ps.tile[(ty + 8 * i) * 33 + tx] = src[(size_t)(r0 + ty + 8 * i) * NN + c0 + tx];
        __syncthreads();
        #pragma unroll
        for (int i = 0; i < 4; i++)
            dst[(size_t)(c0 + ty + 8 * i) * NN + r0 + tx] = ps.tile[tx * 33 + ty + 8 * i];
    } else {
        int id = bid - 1344;
        const float* W; u16 *Dh, *Dl; int K, N, mat, s, nt;
        if (id < 1280) {
            int seg = id / 320, local = id % 320;
            mat = local >> 5; int rem = local & 31; s = rem >> 2; nt = rem & 3;
            K = 256; N = 256;
            W  = seg == 0 ? Wq : seg == 1 ? Wk : seg == 2 ? Wv : Wc;
            Dh = seg == 0 ? qh : seg == 1 ? kh : seg == 2 ? vh : ch;
            Dl = seg == 0 ? ql : seg == 1 ? kl_ : seg == 2 ? vl : cl;
        } else if (id < 1920) {
            int local = id - 1280;
            mat = local >> 6; int rem = local & 63; s = rem >> 3; nt = rem & 7;
            K = 256; N = 512; W = W1; Dh = f1h; Dl = f1l;
        } else {
            int local = id - 1920;
            mat = local >> 6; int rem = local & 63; s = rem >> 2; nt = rem & 3;
            K = 512; N = 256; W = W2; Dh = f2h; Dl = f2l;
        }
        int kk = t >> 3, nl = (t & 7) * 8;
        const float* p = W + (size_t)mat * K * N + (size_t)(s * 32 + kk) * N + nt * 64 + nl;
        float4 f0 = *(const float4*)p;
        float4 f1v = *(const float4*)(p + 4);
        float fv[8] = {f0.x, f0.y, f0.z, f0.w, f1v.x, f1v.y, f1v.z, f1v.w};
        #pragma unroll
        for (int i = 0; i < 8; i++) bsplit(fv[i], ps.wp.th[(nl + i) * 40 + kk], ps.wp.tl[(nl + i) * 40 + kk]);
        __syncthreads();
        int n = t >> 2, ko = (t & 3) * 8;
        size_t dbase = (size_t)mat * K * N + (size_t)s * N * 32 + (size_t)nt * 64 * 32
                     + (size_t)n * 32 + ko;
        *(us8*)(Dh + dbase) = *(const us8*)&ps.wp.th[n * 40 + ko];
        *(us8*)(Dl + dbase) = *(const us8*)&ps.wp.tl[n * 40 + ko];
    }
}

__global__ void k_final(const float* __restrict__ pmin, const float* __restrict__ pmax,
                        const float* __restrict__ Wedge, const float* __restrict__ bedge,
                        const float* __restrict__ Wmix, float* __restrict__ stats,
                        float* __restrict__ c1c0) {
    int t = threadIdx.x;
    if (t < 4) {
        float mn = 1e30f, mx = -1e30f;
        #pragma unroll
        for (int p = 0; p < 16; p++) {
            mn = fminf(mn, pmin[t * 16 + p]);
            mx = fmaxf(mx, pmax[t * 16 + p]);
        }
        float rng = mx - mn;
        if (rng == 0.f) rng = 1.f;
        stats[t] = mn;
        stats[4 + t] = 1.f / rng;
    } else if (t >= 64 && t < 64 + LAYERS * 2 * H) {
        int p = t - 64;
        int lj = p >> 4, h = p & 15;
        float c1 = 0.f, c0 = 0.f;
        for (int e = 0; e < E; e++) {
            float wm = Wmix[(lj * E + e) * H + h];
            c1 += Wedge[e] * wm;
            c0 += bedge[e] * wm;
        }
        c1c0[p] = c1;
        c1c0[160 + p] = c0;
    }
}

// ================= fused QKV + attention =================
// grid (BB, H*2 (head, n-half), 2 j), 256 thr. q/k/v never hit global.
__global__ __launch_bounds__(256) void k_qkvattn(
    const u16* __restrict__ rowh, const u16* __restrict__ rowl,
    const u16* __restrict__ colh, const u16* __restrict__ coll,
    const u16* __restrict__ WqTh, const u16* __restrict__ WqTl,
    const u16* __restrict__ WkTh, const u16* __restrict__ WkTl,
    const u16* __restrict__ WvTh, const u16* __restrict__ WvTl, int lb2,
    const float* __restrict__ data, const float* __restrict__ dataT,
    const float* __restrict__ stats, const float* __restrict__ c1c0,
    u16* __restrict__ atth0, u16* __restrict__ attl0,
    u16* __restrict__ atth1, u16* __restrict__ attl1) {
    __shared__ float skl[256 * 20];
    __shared__ float svl[256 * 20];
    __shared__ float sql[128 * 20];
    int b = blockIdx.x;
    int h = blockIdx.y >> 1, nh = blockIdx.y & 1;
    int j = blockIdx.z;
    int t = threadIdx.x;
    int lane = t & 63, w = t >> 6;
    int quad = lane >> 4, l16 = lane & 15;
    const u16* kvh = j ? rowh : colh;
    const u16* kvl = j ? rowl : coll;
    const u16* qsh = j ? colh : rowh;
    const u16* qsl = j ? coll : rowl;
    size_t woff = (size_t)(lb2 + j) * E * E;
    {
        f32x4 acc[4][1] = {};
        wave_gemm<4, 1>(kvh, kvl, WkTh + woff, WkTl + woff, b * 256 + w * 64, h * 16, E, E, acc);
        #pragma unroll
        for (int mt = 0; mt < 4; mt++)
            #pragma unroll
            for (int r = 0; r < 4; r++)
                skl[(w * 64 + mt * 16 + quad * 4 + r) * 20 + l16] = acc[mt][0][r];
    }
    {
        f32x4 acc[4][1] = {};
        wave_gemm<4, 1>(kvh, kvl, WvTh + woff, WvTl + woff, b * 256 + w * 64, h * 16, E, E, acc);
        #pragma unroll
        for (int mt = 0; mt < 4; mt++)
            #pragma unroll
            for (int r = 0; r < 4; r++)
                svl[(w * 64 + mt * 16 + quad * 4 + r) * 20 + l16] = acc[mt][0][r];
    }
    {
        f32x4 acc[2][1] = {};
        wave_gemm<2, 1>(qsh, qsl, WqTh + woff, WqTl + woff, b * 256 + nh * 128 + w * 32, h * 16, E, E, acc);
        #pragma unroll
        for (int mt = 0; mt < 2; mt++)
            #pragma unroll
            for (int r = 0; r < 4; r++)
                sql[(w * 32 + mt * 16 + quad * 4 + r) * 20 + l16] = acc[mt][0][r];
    }
    __syncthreads();
    float mn = stats[b], inv = stats[4 + b];
    float c1 = c1c0[(lb2 + j) * 16 + h];
    float c0 = c1c0[160 + (lb2 + j) * 16 + h];
    float c1p = inv * c1;
    float c0p = c0 - mn * c1p;
    int r = lane >> 3, ml = lane & 7;
    const float* edgebase = (j ? dataT : data) + (size_t)b * NN * NN;
    for (int pass = 0; pass < 4; pass++) {
        int nloc = pass * 32 + w * 8 + r;
        int n = nh * 128 + nloc;
        float qr[16];
        #pragma unroll
        for (int d4 = 0; d4 < 4; d4++) {
            float4 q4 = *(const float4*)&sql[nloc * 20 + d4 * 4];
            qr[d4 * 4 + 0] = q4.x; qr[d4 * 4 + 1] = q4.y;
            qr[d4 * 4 + 2] = q4.z; qr[d4 * 4 + 3] = q4.w;
        }
        const float* pedge = edgebase + (size_t)n * NN;
        float sum = 0.f;
        float acc[16] = {};
        for (int i = 0; i < 32; i++) {
            int m = ml + 8 * i;
            float4 ka = *(const float4*)&skl[m * 20 + 0];
            float4 kb = *(const float4*)&skl[m * 20 + 4];
            float4 kc = *(const float4*)&skl[m * 20 + 8];
            float4 kd = *(const float4*)&skl[m * 20 + 12];
            float s0 = qr[0] * ka.x + qr[1] * ka.y + qr[2] * ka.z + qr[3] * ka.w;
            float s1 = qr[4] * kb.x + qr[5] * kb.y + qr[6] * kb.z + qr[7] * kb.w;
            float s2 = qr[8] * kc.x + qr[9] * kc.y + qr[10] * kc.z + qr[11] * kc.w;
            float s3 = qr[12] * kd.x + qr[13] * kd.y + qr[14] * kd.z + qr[15] * kd.w;
            float s = ((s0 + s1) + (s2 + s3)) * 0.25f + pedge[m] * c1p + c0p;
            float e = __expf(s);
            sum += e;
            float4 va = *(const float4*)&svl[m * 20 + 0];
            float4 vb = *(const float4*)&svl[m * 20 + 4];
            float4 vc = *(const float4*)&svl[m * 20 + 8];
            float4 vd = *(const float4*)&svl[m * 20 + 12];
            acc[0] += e * va.x;  acc[1] += e * va.y;  acc[2] += e * va.z;  acc[3] += e * va.w;
            acc[4] += e * vb.x;  acc[5] += e * vb.y;  acc[6] += e * vb.z;  acc[7] += e * vb.w;
            acc[8] += e * vc.x;  acc[9] += e * vc.y;  acc[10] += e * vc.z; acc[11] += e * vc.w;
            acc[12] += e * vd.x; acc[13] += e * vd.y; acc[14] += e * vd.z; acc[15] += e * vd.w;
        }
        #pragma unroll
        for (int mask = 1; mask <= 4; mask <<= 1) {
            sum += __shfl_xor(sum, mask);
            #pragma unroll
            for (int d = 0; d < 16; d++) acc[d] += __shfl_xor(acc[d], mask);
        }
        if (ml == 0) {
            float invs = 1.f / sum;
            u16 hh[16], ll[16];
            #pragma unroll
            for (int d = 0; d < 16; d++) bsplit(acc[d] * invs, hh[d], ll[d]);
            size_t base = ((size_t)(b * NN + n) * E) + h * DD;
            u16* oh = (j ? atth1 : atth0) + base;
            u16* ol = (j ? attl1 : attl0) + base;
            *(us8*)oh = *(const us8*)&hh[0];
            *(us8*)(oh + 8) = *(const us8*)&hh[8];
            *(us8*)ol = *(const us8*)&ll[0];
            *(us8*)(ol + 8) = *(const us8*)&ll[8];
        }
    }
}

// ================= GEMM (M=256 rows of one batch) + InstanceNorm fused =================
// grid (BB, 8 col-groups of 32, 2 j), 256 thr. Used for comb+IN1 and FF2+IN2.
__global__ __launch_bounds__(256) void k_rowIN(
    const u16* __restrict__ Ah0, const u16* __restrict__ Al0,
    const u16* __restrict__ Ah1, const u16* __restrict__ Al1,
    const u16* __restrict__ Bh, const u16* __restrict__ Bl, int lb2, long wstride,
    const float* __restrict__ biasl,
    const float* __restrict__ R0, const float* __restrict__ R1,
    const float* __restrict__ inw, const float* __restrict__ inb,
    float* Of0, float* Of1,
    u16* Oh0, u16* Ol0, u16* Oh1, u16* Ol1,
    float* fout, int K) {
    __shared__ float ybuf[256 * 33];
    __shared__ float pr[256], pr2[256];
    int b = blockIdx.x, ng = blockIdx.y, j = blockIdx.z;
    int t = threadIdx.x, lane = t & 63, w = t >> 6;
    int quad = lane >> 4, l16 = lane & 15;
    const u16* Ah = j ? Ah1 : Ah0;
    const u16* Al = j ? Al1 : Al0;
    const u16* Bph = Bh + (size_t)(lb2 + j) * wstride;
    const u16* Bpl = Bl + (size_t)(lb2 + j) * wstride;
    const float* R = j ? R1 : R0;
    const float* bias = biasl + (size_t)(lb2 + j) * E;
    f32x4 acc[4][2] = {};
    wave_gemm<4, 2>(Ah, Al, Bph, Bpl, b * 256 + w * 64, ng * 32, K, E, acc);
    #pragma unroll
    for (int mt = 0; mt < 4; mt++)
        #pragma unroll
        for (int nt = 0; nt < 2; nt++) {
            int colg = ng * 32 + nt * 16 + l16;
            float bia = bias[colg];
            #pragma unroll
            for (int r = 0; r < 4; r++) {
                int rowl = w * 64 + mt * 16 + quad * 4 + r;
                float v = acc[mt][nt][r] + bia + R[(size_t)(b * 256 + rowl) * E + colg];
                ybuf[rowl * 33 + nt * 16 + l16] = v;
            }
        }
    __syncthreads();
    int c = t & 31, seg = t >> 5;
    float s = 0.f, s2 = 0.f;
    for (int i = 0; i < 32; i++) {
        float v = ybuf[(seg * 32 + i) * 33 + c];
        s += v;
        s2 += v * v;
    }
    pr[c * 8 + seg] = s;
    pr2[c * 8 + seg] = s2;
    __syncthreads();
    float st = 0.f, st2 = 0.f;
    #pragma unroll
    for (int g = 0; g < 8; g++) { st += pr[c * 8 + g]; st2 += pr2[c * 8 + g]; }
    int colg = ng * 32 + c;
    float mu = st * (1.f / NN);
    float var = fmaxf(st2 * (1.f / NN) - mu * mu, 0.f);
    float scale = inw[(size_t)(lb2 + j) * E + colg] * rsqrtf(var + 1e-5f);
    float shift = inb[(size_t)(lb2 + j) * E + colg] - mu * scale;
    float* Of = Of0 ? (j ? Of1 : Of0) : nullptr;
    u16* Oh = j ? Oh1 : Oh0;
    u16* Ol = j ? Ol1 : Ol0;
    for (int i = 0; i < 32; i++) {
        int rowl = seg * 32 + i;
        float vv = ybuf[rowl * 33 + c] * scale + shift;
        size_t gidx = (size_t)(b * 256 + rowl) * E + colg;
        if (Of) Of[gidx] = vv;
        u16 hh, ll;
        bsplit(vv, hh, ll);
        Oh[gidx] = hh;
        Ol[gidx] = ll;
        if (fout) fout[(size_t)j * ((size_t)BB * NN * E) + gidx] = vv;
    }
}

// ================= FF1 (relu, hi/lo out) =================
// grid (16 m-blocks of 64, 4 n-blocks of 128, 2 j), 256 thr
__global__ __launch_bounds__(256) void k_ff1(
    const u16* __restrict__ Ah0, const u16* __restrict__ Al0,
    const u16* __restrict__ Ah1, const u16* __restrict__ Al1,
    const u16* __restrict__ Bh, const u16* __restrict__ Bl, int lb2,
    const float* __restrict__ b1,
    u16* Oh0, u16* Ol0, u16* Oh1, u16* Ol1) {
    int mb = blockIdx.x, nb = blockIdx.y, j = blockIdx.z;
    int t = threadIdx.x, lane = t & 63, w = t >> 6;
    int quad = lane >> 4, l16 = lane & 15;
    const u16* Ah = j ? Ah1 : Ah0;
    const u16* Al = j ? Al1 : Al0;
    const u16* Bph = Bh + (size_t)(lb2 + j) * E * FFH;
    const u16* Bpl = Bl + (size_t)(lb2 + j) * E * FFH;
    const float* bias = b1 + (size_t)(lb2 + j) * FFH;
    u16* Oh = j ? Oh1 : Oh0;
    u16* Ol = j ? Ol1 : Ol0;
    f32x4 acc[4][2] = {};
    wave_gemm<4, 2>(Ah, Al, Bph, Bpl, mb * 64, nb * 128 + w * 32, E, FFH, acc);
    #pragma unroll
    for (int mt = 0; mt < 4; mt++)
        #pragma unroll
        for (int nt = 0; nt < 2; nt++) {
            int colg = nb * 128 + w * 32 + nt * 16 + l16;
            float bia = bias[colg];
            #pragma unroll
            for (int r = 0; r < 4; r++) {
                int row = mb * 64 + mt * 16 + quad * 4 + r;
                float v = fmaxf(acc[mt][nt][r] + bia, 0.f);
                u16 hh, ll;
                bsplit(v, hh, ll);
                Oh[(size_t)row * FFH + colg] = hh;
                Ol[(size_t)row * FFH + colg] = ll;
            }
        }
}

// ---------------- host ----------------

extern "C" void kernel_launch(void* const* d_in, const int* in_sizes, int n_in,
                              void* d_out, int out_size, void* d_ws, size_t ws_size,
                              hipStream_t stream) {
    const float* data      = (const float*)d_in[0];
    const float* node_rand = (const float*)d_in[1];
    const float* Wnode     = (const float*)d_in[2];
    const float* bnode     = (const float*)d_in[3];
    const float* Wedge     = (const float*)d_in[4];
    const float* bedge     = (const float*)d_in[5];
    const float* Wq        = (const float*)d_in[6];
    const float* Wk        = (const float*)d_in[7];
    const float* Wv        = (const float*)d_in[8];
    const float* Wcomb     = (const float*)d_in[9];
    const float* bcomb     = (const float*)d_in[10];
    const float* n1w       = (const float*)d_in[11];
    const float* n1b       = (const float*)d_in[12];
    const float* W1        = (const float*)d_in[13];
    const float* b1        = (const float*)d_in[14];
    const float* W2        = (const float*)d_in[15];
    const float* b2        = (const float*)d_in[16];
    const float* n2w       = (const float*)d_in[17];
    const float* n2b       = (const float*)d_in[18];
    const float* Wmix      = (const float*)d_in[19];
    float* out = (float*)d_out;

    float* ws = (float*)d_ws;
    const size_t T = (size_t)MROWS * E;      // 262144
    const size_t TF = (size_t)MROWS * FFH;   // 524288
    float* dataT = ws + 0 * T;
    float* row   = ws + 1 * T;
    float* col   = ws + 2 * T;
    float* o1f0  = ws + 3 * T;
    float* o1f1  = ws + 4 * T;
    float* stats = ws + 5 * T;
    float* pmin  = stats + 8;
    float* pmax  = pmin + 64;
    float* c1c0  = pmax + 64;
    u16* us = (u16*)(ws + 5 * T + 512);
    auto nxt = [&](size_t n) { u16* p = us; us += n; return p; };
    u16* rowh = nxt(T);  u16* rowl = nxt(T);
    u16* colh = nxt(T);  u16* coll = nxt(T);
    u16* atth0 = nxt(T); u16* attl0 = nxt(T);
    u16* atth1 = nxt(T); u16* attl1 = nxt(T);
    u16* o1h0 = nxt(T);  u16* o1l0 = nxt(T);
    u16* o1h1 = nxt(T);  u16* o1l1 = nxt(T);
    u16* ffhh0 = nxt(TF); u16* ffhl0 = nxt(TF);
    u16* ffhh1 = nxt(TF); u16* ffhl1 = nxt(TF);
    const size_t EE10 = (size_t)10 * E * E;
    const size_t EF10 = (size_t)10 * E * FFH;
    u16* WqTh = nxt(EE10); u16* WqTl = nxt(EE10);
    u16* WkTh = nxt(EE10); u16* WkTl = nxt(EE10);
    u16* WvTh = nxt(EE10); u16* WvTl = nxt(EE10);
    u16* WcTh = nxt(EE10); u16* WcTl = nxt(EE10);
    u16* W1Th = nxt(EF10); u16* W1Tl = nxt(EF10);
    u16* W2Th = nxt(EF10); u16* W2Tl = nxt(EF10);

    k_prep<<<3904, 256, 0, stream>>>(data, node_rand, Wnode, bnode,
                                     Wq, Wk, Wv, Wcomb, W1, W2,
                                     pmin, pmax, row, col, rowh, rowl, colh, coll, dataT,
                                     WqTh, WqTl, WkTh, WkTl, WvTh, WvTl,
                                     WcTh, WcTl, W1Th, W1Tl, W2Th, W2Tl);
    k_final<<<1, 256, 0, stream>>>(pmin, pmax, Wedge, bedge, Wmix, stats, c1c0);

    for (int l = 0; l < LAYERS; l++) {
        int lb2 = l * 2;
        k_qkvattn<<<dim3(BB, H * 2, 2), 256, 0, stream>>>(
            rowh, rowl, colh, coll,
            WqTh, WqTl, WkTh, WkTl, WvTh, WvTl, lb2,
            data, dataT, stats, c1c0,
            atth0, attl0, atth1, attl1);
        // comb + IN1
        k_rowIN<<<dim3(BB, 8, 2), 256, 0, stream>>>(
            atth0, attl0, atth1, attl1,
            WcTh, WcTl, lb2, (long)E * E,
            bcomb, row, col, n1w, n1b,
            o1f0, o1f1, o1h0, o1l0, o1h1, o1l1,
            nullptr, E);
        k_ff1<<<dim3(16, 4, 2), 256, 0, stream>>>(
            o1h0, o1l0, o1h1, o1l1,
            W1Th, W1Tl, lb2, b1,
            ffhh0, ffhl0, ffhh1, ffhl1);
        // FF2 + IN2 (writes row/col fp32 + hi/lo, final layer also writes out)
        k_rowIN<<<dim3(BB, 8, 2), 256, 0, stream>>>(
            ffhh0, ffhl0, ffhh1, ffhl1,
            W2Th, W2Tl, lb2, (long)FFH * E,
            b2, o1f0, o1f1, n2w, n2b,
            row, col, rowh, rowl, colh, coll,
            (l == LAYERS - 1) ? out : nullptr, FFH);
    }
}

// Round 10
// 528.146 us; speedup vs baseline: 4.2728x; 1.3249x over previous
//
#include <hip/hip_runtime.h>
#include <hip/hip_bf16.h>

#define E 256
#define H 16
#define DD 16
#define FFH 512
#define LAYERS 5
#define BB 4
#define NN 256
#define MROWS 1024  // B*N

typedef __attribute__((ext_vector_type(8))) short bfrag;
typedef __attribute__((ext_vector_type(4))) float f32x4;
typedef __attribute__((ext_vector_type(8))) unsigned short us8;
typedef unsigned short u16;

__device__ __forceinline__ void bsplit(float v, u16& h, u16& l) {
    unsigned u = __float_as_uint(v);
    u16 hh = (u16)((u + 0x7fffu + ((u >> 16) & 1u)) >> 16);
    float r = v - __uint_as_float((unsigned)hh << 16);
    unsigned u2 = __float_as_uint(r);
    h = hh;
    l = (u16)((u2 + 0x7fffu + ((u2 >> 16) & 1u)) >> 16);
}

// ================= fused prep (minmax | emb | dataT | wprep) =================
union PrepS {
    float tile[32 * 33];
    struct { u16 th[64 * 40], tl[64 * 40]; } wp;
    struct { float smin[4], smax[4]; } mm;
};

__global__ __launch_bounds__(256) void k_prep(
    const float* __restrict__ data, const float* __restrict__ node_rand,
    const float* __restrict__ Wnode, const float* __restrict__ bnode,
    const float* __restrict__ Wq, const float* __restrict__ Wk, const float* __restrict__ Wv,
    const float* __restrict__ Wc, const float* __restrict__ W1, const float* __restrict__ W2,
    float* __restrict__ pmin, float* __restrict__ pmax,
    float* __restrict__ rowb, float* __restrict__ colb,
    u16* rowh, u16* rowl, u16* colh, u16* coll,
    float* __restrict__ dataT,
    u16* qh, u16* ql, u16* kh, u16* kl_, u16* vh, u16* vl,
    u16* ch, u16* cl, u16* f1h, u16* f1l, u16* f2h, u16* f2l) {
    __shared__ PrepS ps;
    int bid = blockIdx.x;
    int t = threadIdx.x;
    if (bid < 64) {
        int b = bid >> 4, p = bid & 15;
        const float* src = data + (size_t)b * NN * NN + p * 4096;
        float lmin = 1e30f, lmax = -1e30f;
        #pragma unroll
        for (int i = 0; i < 16; i++) {
            float v = src[t + i * 256];
            lmin = fminf(lmin, v);
            lmax = fmaxf(lmax, v);
        }
        #pragma unroll
        for (int off = 32; off; off >>= 1) {
            lmin = fminf(lmin, __shfl_down(lmin, off));
            lmax = fmaxf(lmax, __shfl_down(lmax, off));
        }
        int wid = t >> 6, lane = t & 63;
        if (lane == 0) { ps.mm.smin[wid] = lmin; ps.mm.smax[wid] = lmax; }
        __syncthreads();
        if (t == 0) {
            pmin[b * 16 + p] = fminf(fminf(ps.mm.smin[0], ps.mm.smin[1]), fminf(ps.mm.smin[2], ps.mm.smin[3]));
            pmax[b * 16 + p] = fmaxf(fmaxf(ps.mm.smax[0], ps.mm.smax[1]), fmaxf(ps.mm.smax[2], ps.mm.smax[3]));
        }
    } else if (bid < 1088) {
        int idx = (bid - 64) * 256 + t;
        int bn = idx >> 8, e = idx & 255;
        float v = node_rand[bn] * Wnode[e] + bnode[e];
        rowb[idx] = v;
        colb[idx] = v;
        u16 h, l;
        bsplit(v, h, l);
        rowh[idx] = h; rowl[idx] = l;
        colh[idx] = h; coll[idx] = l;
    } else if (bid < 1344) {
        int local = bid - 1088;
        int bx = local & 7, by = (local >> 3) & 7, b = local >> 6;
        int r0 = by * 32, c0 = bx * 32;
        int tx = t & 31, ty = t >> 5;
        const float* src = data + (size_t)b * NN * NN;
        float* dst = dataT + (size_t)b * NN * NN;
        #pragma unroll
        for (int i = 0; i < 4; i++)
            ps.tile[(ty + 8 * i) * 33 + tx] = src[(size_t)(r0 + ty + 8 * i) * NN + c0 + tx];
        __syncthreads();
        #pragma unroll
        for (int i = 0; i < 4; i++)
            dst[(size_t)(c0 + ty + 8 * i) * NN + r0 + tx] = ps.tile[tx * 33 + ty + 8 * i];
    } else {
        int id = bid - 1344;
        const float* W; u16 *Dh, *Dl; int K, N, mat, s, nt;
        if (id < 1280) {
            int seg = id / 320, local = id % 320;
            mat = local >> 5; int rem = local & 31; s = rem >> 2; nt = rem & 3;
            K = 256; N = 256;
            W  = seg == 0 ? Wq : seg == 1 ? Wk : seg == 2 ? Wv : Wc;
            Dh = seg == 0 ? qh : seg == 1 ? kh : seg == 2 ? vh : ch;
            Dl = seg == 0 ? ql : seg == 1 ? kl_ : seg == 2 ? vl : cl;
        } else if (id < 1920) {
            int local = id - 1280;
            mat = local >> 6; int rem = local & 63; s = rem >> 3; nt = rem & 7;
            K = 256; N = 512; W = W1; Dh = f1h; Dl = f1l;
        } else {
            int local = id - 1920;
            mat = local >> 6; int rem = local & 63; s = rem >> 2; nt = rem & 3;
            K = 512; N = 256; W = W2; Dh = f2h; Dl = f2l;
        }
        int kk = t >> 3, nl = (t & 7) * 8;
        const float* p = W + (size_t)mat * K * N + (size_t)(s * 32 + kk) * N + nt * 64 + nl;
        float4 f0 = *(const float4*)p;
        float4 f1v = *(const float4*)(p + 4);
        float fv[8] = {f0.x, f0.y, f0.z, f0.w, f1v.x, f1v.y, f1v.z, f1v.w};
        #pragma unroll
        for (int i = 0; i < 8; i++) bsplit(fv[i], ps.wp.th[(nl + i) * 40 + kk], ps.wp.tl[(nl + i) * 40 + kk]);
        __syncthreads();
        int n = t >> 2, ko = (t & 3) * 8;
        size_t dbase = (size_t)mat * K * N + (size_t)s * N * 32 + (size_t)nt * 64 * 32
                     + (size_t)n * 32 + ko;
        *(us8*)(Dh + dbase) = *(const us8*)&ps.wp.th[n * 40 + ko];
        *(us8*)(Dl + dbase) = *(const us8*)&ps.wp.tl[n * 40 + ko];
    }
}

__global__ void k_final(const float* __restrict__ pmin, const float* __restrict__ pmax,
                        const float* __restrict__ Wedge, const float* __restrict__ bedge,
                        const float* __restrict__ Wmix, float* __restrict__ stats,
                        float* __restrict__ c1c0) {
    int t = threadIdx.x;
    if (t < 4) {
        float mn = 1e30f, mx = -1e30f;
        #pragma unroll
        for (int p = 0; p < 16; p++) {
            mn = fminf(mn, pmin[t * 16 + p]);
            mx = fmaxf(mx, pmax[t * 16 + p]);
        }
        float rng = mx - mn;
        if (rng == 0.f) rng = 1.f;
        stats[t] = mn;
        stats[4 + t] = 1.f / rng;
    } else if (t >= 64 && t < 64 + LAYERS * 2 * H) {
        int p = t - 64;
        int lj = p >> 4, h = p & 15;
        float c1 = 0.f, c0 = 0.f;
        for (int e = 0; e < E; e++) {
            float wm = Wmix[(lj * E + e) * H + h];
            c1 += Wedge[e] * wm;
            c0 += bedge[e] * wm;
        }
        c1c0[p] = c1;
        c1c0[160 + p] = c0;
    }
}

// ================= LDS-staged MFMA GEMM (R7 engine): 64x64 tile =================
__device__ __forceinline__ void mfma_gemm(const u16* __restrict__ Ah, const u16* __restrict__ Al,
                                          const u16* __restrict__ Bh, const u16* __restrict__ Bl,
                                          const float* __restrict__ bias,
                                          float* __restrict__ Cf, u16* __restrict__ Ch,
                                          u16* __restrict__ Cl, int K, int Ncols, int relu) {
    __shared__ u16 AsH[64 * 40], AsL[64 * 40], BsH[64 * 40], BsL[64 * 40];
    int t = threadIdx.x;
    int lane = t & 63, wave = t >> 6;
    int quad = lane >> 4, l16 = lane & 15;
    int wy = wave >> 1, wx = wave & 1;
    int mBase = blockIdx.x * 64, nBase = blockIdx.y * 64;
    f32x4 acc00 = {0.f, 0.f, 0.f, 0.f}, acc01 = acc00, acc10 = acc00, acc11 = acc00;
    int ar = t >> 2, aks = (t & 3) * 8;
    const int nslab = K >> 5;
    const u16* apH = Ah + (size_t)(mBase + ar) * K + aks;
    const u16* apL = Al + (size_t)(mBase + ar) * K + aks;
    us8 rah = *(const us8*)apH;
    us8 ral = *(const us8*)apL;
    us8 rbh = *(const us8*)(Bh + (size_t)nBase * 32 + t * 8);
    us8 rbl = *(const us8*)(Bl + (size_t)nBase * 32 + t * 8);
    for (int s = 0; s < nslab; s++) {
        __syncthreads();
        *(us8*)&AsH[ar * 40 + aks] = rah;
        *(us8*)&AsL[ar * 40 + aks] = ral;
        *(us8*)&BsH[ar * 40 + aks] = rbh;
        *(us8*)&BsL[ar * 40 + aks] = rbl;
        __syncthreads();
        if (s + 1 < nslab) {
            rah = *(const us8*)(apH + (s + 1) * 32);
            ral = *(const us8*)(apL + (s + 1) * 32);
            rbh = *(const us8*)(Bh + ((size_t)(s + 1) * Ncols + nBase) * 32 + t * 8);
            rbl = *(const us8*)(Bl + ((size_t)(s + 1) * Ncols + nBase) * 32 + t * 8);
        }
        bfrag a_h0 = *(const bfrag*)&AsH[(wy * 32 + l16) * 40 + quad * 8];
        bfrag a_h1 = *(const bfrag*)&AsH[(wy * 32 + 16 + l16) * 40 + quad * 8];
        bfrag a_l0 = *(const bfrag*)&AsL[(wy * 32 + l16) * 40 + quad * 8];
        bfrag a_l1 = *(const bfrag*)&AsL[(wy * 32 + 16 + l16) * 40 + quad * 8];
        bfrag b_h0 = *(const bfrag*)&BsH[(wx * 32 + l16) * 40 + quad * 8];
        bfrag b_h1 = *(const bfrag*)&BsH[(wx * 32 + 16 + l16) * 40 + quad * 8];
        bfrag b_l0 = *(const bfrag*)&BsL[(wx * 32 + l16) * 40 + quad * 8];
        bfrag b_l1 = *(const bfrag*)&BsL[(wx * 32 + 16 + l16) * 40 + quad * 8];
        acc00 = __builtin_amdgcn_mfma_f32_16x16x32_bf16(a_h0, b_h0, acc00, 0, 0, 0);
        acc01 = __builtin_amdgcn_mfma_f32_16x16x32_bf16(a_h0, b_h1, acc01, 0, 0, 0);
        acc10 = __builtin_amdgcn_mfma_f32_16x16x32_bf16(a_h1, b_h0, acc10, 0, 0, 0);
        acc11 = __builtin_amdgcn_mfma_f32_16x16x32_bf16(a_h1, b_h1, acc11, 0, 0, 0);
        acc00 = __builtin_amdgcn_mfma_f32_16x16x32_bf16(a_h0, b_l0, acc00, 0, 0, 0);
        acc01 = __builtin_amdgcn_mfma_f32_16x16x32_bf16(a_h0, b_l1, acc01, 0, 0, 0);
        acc10 = __builtin_amdgcn_mfma_f32_16x16x32_bf16(a_h1, b_l0, acc10, 0, 0, 0);
        acc11 = __builtin_amdgcn_mfma_f32_16x16x32_bf16(a_h1, b_l1, acc11, 0, 0, 0);
        acc00 = __builtin_amdgcn_mfma_f32_16x16x32_bf16(a_l0, b_h0, acc00, 0, 0, 0);
        acc01 = __builtin_amdgcn_mfma_f32_16x16x32_bf16(a_l0, b_h1, acc01, 0, 0, 0);
        acc10 = __builtin_amdgcn_mfma_f32_16x16x32_bf16(a_l1, b_h0, acc10, 0, 0, 0);
        acc11 = __builtin_amdgcn_mfma_f32_16x16x32_bf16(a_l1, b_h1, acc11, 0, 0, 0);
    }
    int col0 = nBase + wx * 32 + l16;
    int col1 = col0 + 16;
    float bia0 = bias ? bias[col0] : 0.f;
    float bia1 = bias ? bias[col1] : 0.f;
    #pragma unroll
    for (int r = 0; r < 4; r++) {
        int row0 = mBase + wy * 32 + quad * 4 + r;
        int row1 = row0 + 16;
        float v00 = acc00[r] + bia0, v01 = acc01[r] + bia1;
        float v10 = acc10[r] + bia0, v11 = acc11[r] + bia1;
        if (relu) {
            v00 = fmaxf(v00, 0.f); v01 = fmaxf(v01, 0.f);
            v10 = fmaxf(v10, 0.f); v11 = fmaxf(v11, 0.f);
        }
        if (Cf) {
            Cf[(size_t)row0 * Ncols + col0] = v00;
            Cf[(size_t)row0 * Ncols + col1] = v01;
            Cf[(size_t)row1 * Ncols + col0] = v10;
            Cf[(size_t)row1 * Ncols + col1] = v11;
        } else {
            u16 h, l;
            bsplit(v00, h, l); Ch[(size_t)row0 * Ncols + col0] = h; Cl[(size_t)row0 * Ncols + col0] = l;
            bsplit(v01, h, l); Ch[(size_t)row0 * Ncols + col1] = h; Cl[(size_t)row0 * Ncols + col1] = l;
            bsplit(v10, h, l); Ch[(size_t)row1 * Ncols + col0] = h; Cl[(size_t)row1 * Ncols + col0] = l;
            bsplit(v11, h, l); Ch[(size_t)row1 * Ncols + col1] = h; Cl[(size_t)row1 * Ncols + col1] = l;
        }
    }
}

// z = j*3 + which(q/k/v); grid (16,4,6)
__global__ __launch_bounds__(256) void k_qkv(const u16* __restrict__ rowh, const u16* __restrict__ rowl,
                                             const u16* __restrict__ colh, const u16* __restrict__ coll,
                                             const u16* __restrict__ WqTh, const u16* __restrict__ WqTl,
                                             const u16* __restrict__ WkTh, const u16* __restrict__ WkTl,
                                             const u16* __restrict__ WvTh, const u16* __restrict__ WvTl,
                                             int lb2,
                                             float* q0, float* k0, float* v0,
                                             float* q1, float* k1, float* v1) {
    int z = blockIdx.z;
    int j = z / 3, w = z % 3;
    const u16* Ah = (w == 0) ? (j ? colh : rowh) : (j ? rowh : colh);
    const u16* Al = (w == 0) ? (j ? coll : rowl) : (j ? rowl : coll);
    const u16* Wh = (w == 0 ? WqTh : (w == 1 ? WkTh : WvTh)) + (size_t)(lb2 + j) * E * E;
    const u16* Wl = (w == 0 ? WqTl : (w == 1 ? WkTl : WvTl)) + (size_t)(lb2 + j) * E * E;
    float* outs[6] = {q0, k0, v0, q1, k1, v1};
    mfma_gemm(Ah, Al, Wh, Wl, nullptr, outs[z], nullptr, nullptr, E, E, 0);
}

// FF1: grid (16,8,2); relu; hi/lo out
__global__ __launch_bounds__(256) void k_ff1(const u16* Ah0, const u16* Al0,
                                             const u16* Ah1, const u16* Al1,
                                             const u16* __restrict__ Bh, const u16* __restrict__ Bl,
                                             int lb2, const float* __restrict__ b1,
                                             u16* Oh0, u16* Ol0, u16* Oh1, u16* Ol1) {
    int j = blockIdx.z;
    mfma_gemm(j ? Ah1 : Ah0, j ? Al1 : Al0,
              Bh + (size_t)(lb2 + j) * E * FFH, Bl + (size_t)(lb2 + j) * E * FFH,
              b1 + (size_t)(lb2 + j) * FFH,
              nullptr, j ? Oh1 : Oh0, j ? Ol1 : Ol0, E, FFH, 1);
}

// ================= fused attention =================
// grid (B*H=64, 8 n-groups of 32, 2 j), 256 thr; 8 lanes per row; out bf16 hi/lo.
__global__ __launch_bounds__(256) void k_attn(const float* __restrict__ q0, const float* __restrict__ k0,
                                              const float* __restrict__ v0, const float* __restrict__ q1,
                                              const float* __restrict__ k1, const float* __restrict__ v1,
                                              const float* __restrict__ data, const float* __restrict__ dataT,
                                              const float* __restrict__ stats,
                                              const float* __restrict__ c1c0, int lj_base,
                                              u16* __restrict__ atth0, u16* __restrict__ attl0,
                                              u16* __restrict__ atth1, u16* __restrict__ attl1) {
    int bh = blockIdx.x;
    int b = bh >> 4, h = bh & 15;
    int ng = blockIdx.y;
    int j = blockIdx.z;
    const float* q = j ? q1 : q0;
    const float* k = j ? k1 : k0;
    const float* v = j ? v1 : v0;
    float mn = stats[b], inv = stats[4 + b];
    float c1 = c1c0[(lj_base + j) * 16 + h];
    float c0 = c1c0[160 + (lj_base + j) * 16 + h];
    float c1p = inv * c1;
    float c0p = c0 - mn * c1p;

    __shared__ float kl[256 * 20];
    __shared__ float vl[256 * 20];
    int t = threadIdx.x;
    {
        int c = t & 3, mb = t >> 2;
        #pragma unroll
        for (int it = 0; it < 4; it++) {
            int m = mb + 64 * it;
            const float* kp = k + ((size_t)(b * NN + m) * E) + h * DD + c * 4;
            const float* vp = v + ((size_t)(b * NN + m) * E) + h * DD + c * 4;
            *(float4*)&kl[m * 20 + c * 4] = *(const float4*)kp;
            *(float4*)&vl[m * 20 + c * 4] = *(const float4*)vp;
        }
    }
    __syncthreads();

    int lane = t & 63, w = t >> 6;
    int r = lane >> 3, ml = lane & 7;
    int n = ng * 32 + w * 8 + r;

    float qr[16];
    const float* qp = q + ((size_t)(b * NN + n) * E) + h * DD;
    #pragma unroll
    for (int d4 = 0; d4 < 4; d4++) {
        float4 q4 = *(const float4*)(qp + d4 * 4);
        qr[d4 * 4 + 0] = q4.x; qr[d4 * 4 + 1] = q4.y;
        qr[d4 * 4 + 2] = q4.z; qr[d4 * 4 + 3] = q4.w;
    }
    const float* pedge = (j ? dataT : data) + (size_t)b * NN * NN + (size_t)n * NN;

    float sum = 0.f;
    float acc[16] = {};
    for (int i = 0; i < 32; i++) {
        int m = ml + 8 * i;
        float4 ka = *(const float4*)&kl[m * 20 + 0];
        float4 kb = *(const float4*)&kl[m * 20 + 4];
        float4 kc = *(const float4*)&kl[m * 20 + 8];
        float4 kd = *(const float4*)&kl[m * 20 + 12];
        float s0 = qr[0] * ka.x + qr[1] * ka.y + qr[2] * ka.z + qr[3] * ka.w;
        float s1 = qr[4] * kb.x + qr[5] * kb.y + qr[6] * kb.z + qr[7] * kb.w;
        float s2 = qr[8] * kc.x + qr[9] * kc.y + qr[10] * kc.z + qr[11] * kc.w;
        float s3 = qr[12] * kd.x + qr[13] * kd.y + qr[14] * kd.z + qr[15] * kd.w;
        float s = ((s0 + s1) + (s2 + s3)) * 0.25f + pedge[m] * c1p + c0p;
        float e = __expf(s);
        sum += e;
        float4 va = *(const float4*)&vl[m * 20 + 0];
        float4 vb = *(const float4*)&vl[m * 20 + 4];
        float4 vc = *(const float4*)&vl[m * 20 + 8];
        float4 vd = *(const float4*)&vl[m * 20 + 12];
        acc[0] += e * va.x;  acc[1] += e * va.y;  acc[2] += e * va.z;  acc[3] += e * va.w;
        acc[4] += e * vb.x;  acc[5] += e * vb.y;  acc[6] += e * vb.z;  acc[7] += e * vb.w;
        acc[8] += e * vc.x;  acc[9] += e * vc.y;  acc[10] += e * vc.z; acc[11] += e * vc.w;
        acc[12] += e * vd.x; acc[13] += e * vd.y; acc[14] += e * vd.z; acc[15] += e * vd.w;
    }
    #pragma unroll
    for (int mask = 1; mask <= 4; mask <<= 1) {
        sum += __shfl_xor(sum, mask);
        #pragma unroll
        for (int d = 0; d < 16; d++) acc[d] += __shfl_xor(acc[d], mask);
    }
    if (ml == 0) {
        float invs = 1.f / sum;
        u16 hh[16], ll[16];
        #pragma unroll
        for (int d = 0; d < 16; d++) bsplit(acc[d] * invs, hh[d], ll[d]);
        size_t base = ((size_t)(b * NN + n) * E) + h * DD;
        u16* oh = (j ? atth1 : atth0) + base;
        u16* ol = (j ? attl1 : attl0) + base;
        *(us8*)oh = *(const us8*)&hh[0];
        *(us8*)(oh + 8) = *(const us8*)&hh[8];
        *(us8*)ol = *(const us8*)&ll[0];
        *(us8*)(ol + 8) = *(const us8*)&ll[8];
    }
}

// ================= fused GEMM(M=256 per batch) + InstanceNorm =================
// grid (BB, 8 col-groups of 32, 2 j), 256 thr = 4 waves.
// LDS-staged A slab (256x32) + B slab (32x32); acc in registers; IN via shfl + LDS.
__global__ __launch_bounds__(256) void k_gemmIN(
    const u16* Ah0, const u16* Al0, const u16* Ah1, const u16* Al1,
    const u16* __restrict__ Bh, const u16* __restrict__ Bl, int lb2, long wstride,
    const float* __restrict__ biasl,
    const float* R0, const float* R1,
    const float* __restrict__ inw, const float* __restrict__ inb,
    float* Of0, float* Of1,
    u16* Oh0, u16* Ol0, u16* Oh1, u16* Ol1,
    float* fout, int K) {
    __shared__ u16 AsH[256 * 40], AsL[256 * 40], BsH[32 * 40], BsL[32 * 40];
    __shared__ float redS[4 * 32], redS2[4 * 32];
    int b = blockIdx.x, ng = blockIdx.y, j = blockIdx.z;
    int t = threadIdx.x, lane = t & 63, w = t >> 6;
    int quad = lane >> 4, l16 = lane & 15;
    const u16* Ah = (j ? Ah1 : Ah0) + (size_t)(b * 256 + t) * K;
    const u16* Al = (j ? Al1 : Al0) + (size_t)(b * 256 + t) * K;
    // per-slab B group base: slab s at (s*E + ng*32)*32
    const u16* Bph = Bh + (size_t)(lb2 + j) * wstride + (size_t)ng * 32 * 32;
    const u16* Bpl = Bl + (size_t)(lb2 + j) * wstride + (size_t)ng * 32 * 32;
    const long bslab = (long)E * 32;  // Ncols=E always for these GEMMs
    f32x4 acc[4][2] = {};
    int nslab = K >> 5;
    int bcol = (t & 127) >> 2, bko = (t & 3) * 8;
    for (int s = 0; s < nslab; s++) {
        us8 va0 = *(const us8*)(Ah + s * 32);
        us8 va1 = *(const us8*)(Ah + s * 32 + 8);
        us8 va2 = *(const us8*)(Ah + s * 32 + 16);
        us8 va3 = *(const us8*)(Ah + s * 32 + 24);
        us8 vl0 = *(const us8*)(Al + s * 32);
        us8 vl1 = *(const us8*)(Al + s * 32 + 8);
        us8 vl2 = *(const us8*)(Al + s * 32 + 16);
        us8 vl3 = *(const us8*)(Al + s * 32 + 24);
        us8 vb = (t < 128) ? *(const us8*)(Bph + (size_t)s * bslab + (t & 127) * 8)
                           : *(const us8*)(Bpl + (size_t)s * bslab + (t & 127) * 8);
        __syncthreads();
        *(us8*)&AsH[t * 40 + 0]  = va0;
        *(us8*)&AsH[t * 40 + 8]  = va1;
        *(us8*)&AsH[t * 40 + 16] = va2;
        *(us8*)&AsH[t * 40 + 24] = va3;
        *(us8*)&AsL[t * 40 + 0]  = vl0;
        *(us8*)&AsL[t * 40 + 8]  = vl1;
        *(us8*)&AsL[t * 40 + 16] = vl2;
        *(us8*)&AsL[t * 40 + 24] = vl3;
        if (t < 128) *(us8*)&BsH[bcol * 40 + bko] = vb;
        else         *(us8*)&BsL[bcol * 40 + bko] = vb;
        __syncthreads();
        #pragma unroll
        for (int mt = 0; mt < 4; mt++) {
            bfrag a_h = *(const bfrag*)&AsH[(w * 64 + mt * 16 + l16) * 40 + quad * 8];
            bfrag a_l = *(const bfrag*)&AsL[(w * 64 + mt * 16 + l16) * 40 + quad * 8];
            #pragma unroll
            for (int nt = 0; nt < 2; nt++) {
                bfrag b_h = *(const bfrag*)&BsH[(nt * 16 + l16) * 40 + quad * 8];
                bfrag b_l = *(const bfrag*)&BsL[(nt * 16 + l16) * 40 + quad * 8];
                acc[mt][nt] = __builtin_amdgcn_mfma_f32_16x16x32_bf16(a_h, b_h, acc[mt][nt], 0, 0, 0);
                acc[mt][nt] = __builtin_amdgcn_mfma_f32_16x16x32_bf16(a_h, b_l, acc[mt][nt], 0, 0, 0);
                acc[mt][nt] = __builtin_amdgcn_mfma_f32_16x16x32_bf16(a_l, b_h, acc[mt][nt], 0, 0, 0);
            }
        }
    }
    // epilogue: bias + residual; column sums
    const float* R = j ? R1 : R0;
    const float* bias = biasl + (size_t)(lb2 + j) * E;
    float cs[2] = {0.f, 0.f}, cs2[2] = {0.f, 0.f};
    #pragma unroll
    for (int nt = 0; nt < 2; nt++) {
        int colg = ng * 32 + nt * 16 + l16;
        float bia = bias[colg];
        #pragma unroll
        for (int mt = 0; mt < 4; mt++) {
            int rbase = b * 256 + w * 64 + mt * 16 + quad * 4;
            #pragma unroll
            for (int r = 0; r < 4; r++) {
                float v = acc[mt][nt][r] + bia + R[(size_t)(rbase + r) * E + colg];
                acc[mt][nt][r] = v;
                cs[nt] += v;
                cs2[nt] += v * v;
            }
        }
    }
    #pragma unroll
    for (int nt = 0; nt < 2; nt++) {
        cs[nt] += __shfl_xor(cs[nt], 16);
        cs[nt] += __shfl_xor(cs[nt], 32);
        cs2[nt] += __shfl_xor(cs2[nt], 16);
        cs2[nt] += __shfl_xor(cs2[nt], 32);
    }
    __syncthreads();
    if (quad == 0) {
        #pragma unroll
        for (int nt = 0; nt < 2; nt++) {
            redS[w * 32 + nt * 16 + l16] = cs[nt];
            redS2[w * 32 + nt * 16 + l16] = cs2[nt];
        }
    }
    __syncthreads();
    float* Of = Of0 ? (j ? Of1 : Of0) : nullptr;
    u16* Oh = j ? Oh1 : Oh0;
    u16* Ol = j ? Ol1 : Ol0;
    #pragma unroll
    for (int nt = 0; nt < 2; nt++) {
        int cloc = nt * 16 + l16;
        int colg = ng * 32 + cloc;
        float st = redS[cloc] + redS[32 + cloc] + redS[64 + cloc] + redS[96 + cloc];
        float st2 = redS2[cloc] + redS2[32 + cloc] + redS2[64 + cloc] + redS2[96 + cloc];
        float mu = st * (1.f / NN);
        float var = fmaxf(st2 * (1.f / NN) - mu * mu, 0.f);
        float scale = inw[(size_t)(lb2 + j) * E + colg] * rsqrtf(var + 1e-5f);
        float shift = inb[(size_t)(lb2 + j) * E + colg] - mu * scale;
        #pragma unroll
        for (int mt = 0; mt < 4; mt++) {
            int rbase = b * 256 + w * 64 + mt * 16 + quad * 4;
            #pragma unroll
            for (int r = 0; r < 4; r++) {
                float vv = acc[mt][nt][r] * scale + shift;
                size_t gidx = (size_t)(rbase + r) * E + colg;
                if (Of) Of[gidx] = vv;
                u16 hh, ll;
                bsplit(vv, hh, ll);
                Oh[gidx] = hh;
                Ol[gidx] = ll;
                if (fout) fout[(size_t)j * ((size_t)BB * NN * E) + gidx] = vv;
            }
        }
    }
}

// ---------------- host ----------------

extern "C" void kernel_launch(void* const* d_in, const int* in_sizes, int n_in,
                              void* d_out, int out_size, void* d_ws, size_t ws_size,
                              hipStream_t stream) {
    const float* data      = (const float*)d_in[0];
    const float* node_rand = (const float*)d_in[1];
    const float* Wnode     = (const float*)d_in[2];
    const float* bnode     = (const float*)d_in[3];
    const float* Wedge     = (const float*)d_in[4];
    const float* bedge     = (const float*)d_in[5];
    const float* Wq        = (const float*)d_in[6];
    const float* Wk        = (const float*)d_in[7];
    const float* Wv        = (const float*)d_in[8];
    const float* Wcomb     = (const float*)d_in[9];
    const float* bcomb     = (const float*)d_in[10];
    const float* n1w       = (const float*)d_in[11];
    const float* n1b       = (const float*)d_in[12];
    const float* W1        = (const float*)d_in[13];
    const float* b1        = (const float*)d_in[14];
    const float* W2        = (const float*)d_in[15];
    const float* b2        = (const float*)d_in[16];
    const float* n2w       = (const float*)d_in[17];
    const float* n2b       = (const float*)d_in[18];
    const float* Wmix      = (const float*)d_in[19];
    float* out = (float*)d_out;

    float* ws = (float*)d_ws;
    const size_t T = (size_t)MROWS * E;      // 262144
    const size_t TF = (size_t)MROWS * FFH;   // 524288
    float* dataT = ws + 0 * T;
    float* row   = ws + 1 * T;
    float* col   = ws + 2 * T;
    float* q0    = ws + 3 * T;
    float* q1    = ws + 4 * T;
    float* k0    = ws + 5 * T;
    float* k1    = ws + 6 * T;
    float* v0    = ws + 7 * T;
    float* v1    = ws + 8 * T;
    float* o1f0  = ws + 9 * T;
    float* o1f1  = ws + 10 * T;
    float* stats = ws + 11 * T;
    float* pmin  = stats + 8;
    float* pmax  = pmin + 64;
    float* c1c0  = pmax + 64;
    u16* us = (u16*)(ws + 11 * T + 512);
    auto nxt = [&](size_t n) { u16* p = us; us += n; return p; };
    u16* rowh = nxt(T);  u16* rowl = nxt(T);
    u16* colh = nxt(T);  u16* coll = nxt(T);
    u16* atth0 = nxt(T); u16* attl0 = nxt(T);
    u16* atth1 = nxt(T); u16* attl1 = nxt(T);
    u16* o1h0 = nxt(T);  u16* o1l0 = nxt(T);
    u16* o1h1 = nxt(T);  u16* o1l1 = nxt(T);
    u16* ffhh0 = nxt(TF); u16* ffhl0 = nxt(TF);
    u16* ffhh1 = nxt(TF); u16* ffhl1 = nxt(TF);
    const size_t EE10 = (size_t)10 * E * E;
    const size_t EF10 = (size_t)10 * E * FFH;
    u16* WqTh = nxt(EE10); u16* WqTl = nxt(EE10);
    u16* WkTh = nxt(EE10); u16* WkTl = nxt(EE10);
    u16* WvTh = nxt(EE10); u16* WvTl = nxt(EE10);
    u16* WcTh = nxt(EE10); u16* WcTl = nxt(EE10);
    u16* W1Th = nxt(EF10); u16* W1Tl = nxt(EF10);
    u16* W2Th = nxt(EF10); u16* W2Tl = nxt(EF10);

    k_prep<<<3904, 256, 0, stream>>>(data, node_rand, Wnode, bnode,
                                     Wq, Wk, Wv, Wcomb, W1, W2,
                                     pmin, pmax, row, col, rowh, rowl, colh, coll, dataT,
                                     WqTh, WqTl, WkTh, WkTl, WvTh, WvTl,
                                     WcTh, WcTl, W1Th, W1Tl, W2Th, W2Tl);
    k_final<<<1, 256, 0, stream>>>(pmin, pmax, Wedge, bedge, Wmix, stats, c1c0);

    for (int l = 0; l < LAYERS; l++) {
        int lb2 = l * 2;
        k_qkv<<<dim3(16, 4, 6), 256, 0, stream>>>(rowh, rowl, colh, coll,
                                                  WqTh, WqTl, WkTh, WkTl, WvTh, WvTl, lb2,
                                                  q0, k0, v0, q1, k1, v1);
        k_attn<<<dim3(64, 8, 2), 256, 0, stream>>>(q0, k0, v0, q1, k1, v1, data, dataT,
                                                   stats, c1c0, lb2,
                                                   atth0, attl0, atth1, attl1);
        k_gemmIN<<<dim3(BB, 8, 2), 256, 0, stream>>>(
            atth0, attl0, atth1, attl1,
            WcTh, WcTl, lb2, (long)E * E,
            bcomb, row, col, n1w, n1b,
            o1f0, o1f1, o1h0, o1l0, o1h1, o1l1,
            nullptr, E);
        k_ff1<<<dim3(16, 8, 2), 256, 0, stream>>>(o1h0, o1l0, o1h1, o1l1,
                                                  W1Th, W1Tl, lb2, b1,
                                                  ffhh0, ffhl0, ffhh1, ffhl1);
        k_gemmIN<<<dim3(BB, 8, 2), 256, 0, stream>>>(
            ffhh0, ffhl0, ffhh1, ffhl1,
            W2Th, W2Tl, lb2, (long)FFH * E,
            b2, o1f0, o1f1, n2w, n2b,
            row, col, rowh, rowl, colh, coll,
            (l == LAYERS - 1) ? out : nullptr, FFH);
    }
}

// Round 11
// 451.474 us; speedup vs baseline: 4.9984x; 1.1698x over previous
//
#include <hip/hip_runtime.h>
#include <hip/hip_bf16.h>

#define E 256
#define H 16
#define DD 16
#define FFH 512
#define LAYERS 5
#define BB 4
#define NN 256
#define MROWS 1024  // B*N

typedef __attribute__((ext_vector_type(8))) short bfrag;
typedef __attribute__((ext_vector_type(4))) float f32x4;
typedef __attribute__((ext_vector_type(8))) unsigned short us8;
typedef unsigned short u16;

__device__ __forceinline__ void bsplit(float v, u16& h, u16& l) {
    unsigned u = __float_as_uint(v);
    u16 hh = (u16)((u + 0x7fffu + ((u >> 16) & 1u)) >> 16);
    float r = v - __uint_as_float((unsigned)hh << 16);
    unsigned u2 = __float_as_uint(r);
    h = hh;
    l = (u16)((u2 + 0x7fffu + ((u2 >> 16) & 1u)) >> 16);
}

// ================= fused prep (minmax | emb | dataT | wprep | mixconst) =================
union PrepS {
    float tile[32 * 33];
    struct { u16 th[64 * 40], tl[64 * 40]; } wp;
    struct { float smin[4], smax[4]; } mm;
};

__global__ __launch_bounds__(256) void k_prep(
    const float* __restrict__ data, const float* __restrict__ node_rand,
    const float* __restrict__ Wnode, const float* __restrict__ bnode,
    const float* __restrict__ Wedge, const float* __restrict__ bedge,
    const float* __restrict__ Wmix,
    const float* __restrict__ Wq, const float* __restrict__ Wk, const float* __restrict__ Wv,
    const float* __restrict__ Wc, const float* __restrict__ W1, const float* __restrict__ W2,
    float* __restrict__ pmin, float* __restrict__ pmax, float* __restrict__ c1c0,
    float* __restrict__ rowb, float* __restrict__ colb,
    u16* rowh, u16* rowl, u16* colh, u16* coll,
    float* __restrict__ dataT,
    u16* qh, u16* ql, u16* kh, u16* kl_, u16* vh, u16* vl,
    u16* ch, u16* cl, u16* f1h, u16* f1l, u16* f2h, u16* f2l) {
    __shared__ PrepS ps;
    int bid = blockIdx.x;
    int t = threadIdx.x;
    if (bid < 64) {
        // minmax stage-1 partials
        int b = bid >> 4, p = bid & 15;
        const float* src = data + (size_t)b * NN * NN + p * 4096;
        float lmin = 1e30f, lmax = -1e30f;
        #pragma unroll
        for (int i = 0; i < 16; i++) {
            float v = src[t + i * 256];
            lmin = fminf(lmin, v);
            lmax = fmaxf(lmax, v);
        }
        #pragma unroll
        for (int off = 32; off; off >>= 1) {
            lmin = fminf(lmin, __shfl_down(lmin, off));
            lmax = fmaxf(lmax, __shfl_down(lmax, off));
        }
        int wid = t >> 6, lane = t & 63;
        if (lane == 0) { ps.mm.smin[wid] = lmin; ps.mm.smax[wid] = lmax; }
        __syncthreads();
        if (t == 0) {
            pmin[b * 16 + p] = fminf(fminf(ps.mm.smin[0], ps.mm.smin[1]), fminf(ps.mm.smin[2], ps.mm.smin[3]));
            pmax[b * 16 + p] = fmaxf(fmaxf(ps.mm.smax[0], ps.mm.smax[1]), fmaxf(ps.mm.smax[2], ps.mm.smax[3]));
        }
    } else if (bid < 1088) {
        int idx = (bid - 64) * 256 + t;
        int bn = idx >> 8, e = idx & 255;
        float v = node_rand[bn] * Wnode[e] + bnode[e];
        rowb[idx] = v;
        colb[idx] = v;
        u16 h, l;
        bsplit(v, h, l);
        rowh[idx] = h; rowl[idx] = l;
        colh[idx] = h; coll[idx] = l;
    } else if (bid < 1344) {
        int local = bid - 1088;
        int bx = local & 7, by = (local >> 3) & 7, b = local >> 6;
        int r0 = by * 32, c0 = bx * 32;
        int tx = t & 31, ty = t >> 5;
        const float* src = data + (size_t)b * NN * NN;
        float* dst = dataT + (size_t)b * NN * NN;
        #pragma unroll
        for (int i = 0; i < 4; i++)
            ps.tile[(ty + 8 * i) * 33 + tx] = src[(size_t)(r0 + ty + 8 * i) * NN + c0 + tx];
        __syncthreads();
        #pragma unroll
        for (int i = 0; i < 4; i++)
            dst[(size_t)(c0 + ty + 8 * i) * NN + r0 + tx] = ps.tile[tx * 33 + ty + 8 * i];
    } else if (bid < 3904) {
        int id = bid - 1344;
        const float* W; u16 *Dh, *Dl; int K, N, mat, s, nt;
        if (id < 1280) {
            int seg = id / 320, local = id % 320;
            mat = local >> 5; int rem = local & 31; s = rem >> 2; nt = rem & 3;
            K = 256; N = 256;
            W  = seg == 0 ? Wq : seg == 1 ? Wk : seg == 2 ? Wv : Wc;
            Dh = seg == 0 ? qh : seg == 1 ? kh : seg == 2 ? vh : ch;
            Dl = seg == 0 ? ql : seg == 1 ? kl_ : seg == 2 ? vl : cl;
        } else if (id < 1920) {
            int local = id - 1280;
            mat = local >> 6; int rem = local & 63; s = rem >> 3; nt = rem & 7;
            K = 256; N = 512; W = W1; Dh = f1h; Dl = f1l;
        } else {
            int local = id - 1920;
            mat = local >> 6; int rem = local & 63; s = rem >> 2; nt = rem & 3;
            K = 512; N = 256; W = W2; Dh = f2h; Dl = f2l;
        }
        int kk = t >> 3, nl = (t & 7) * 8;
        const float* p = W + (size_t)mat * K * N + (size_t)(s * 32 + kk) * N + nt * 64 + nl;
        float4 f0 = *(const float4*)p;
        float4 f1v = *(const float4*)(p + 4);
        float fv[8] = {f0.x, f0.y, f0.z, f0.w, f1v.x, f1v.y, f1v.z, f1v.w};
        #pragma unroll
        for (int i = 0; i < 8; i++) bsplit(fv[i], ps.wp.th[(nl + i) * 40 + kk], ps.wp.tl[(nl + i) * 40 + kk]);
        __syncthreads();
        int n = t >> 2, ko = (t & 3) * 8;
        size_t dbase = (size_t)mat * K * N + (size_t)s * N * 32 + (size_t)nt * 64 * 32
                     + (size_t)n * 32 + ko;
        *(us8*)(Dh + dbase) = *(const us8*)&ps.wp.th[n * 40 + ko];
        *(us8*)(Dl + dbase) = *(const us8*)&ps.wp.tl[n * 40 + ko];
    } else {
        // mix constants: c1[lj,h] = sum_e Wedge[e]*Wmix[lj,e,h]; c0 likewise with bedge
        if (t < LAYERS * 2 * H) {
            int lj = t >> 4, h = t & 15;
            float c1 = 0.f, c0 = 0.f;
            for (int e = 0; e < E; e++) {
                float wm = Wmix[(lj * E + e) * H + h];
                c1 += Wedge[e] * wm;
                c0 += bedge[e] * wm;
            }
            c1c0[t] = c1;
            c1c0[160 + t] = c0;
        }
    }
}

// ================= LDS-staged MFMA GEMM (proven 461us engine): 64x64 tile =================
__device__ __forceinline__ void mfma_gemm(const u16* __restrict__ Ah, const u16* __restrict__ Al,
                                          const u16* __restrict__ Bh, const u16* __restrict__ Bl,
                                          const float* __restrict__ bias, const float* __restrict__ R,
                                          float* __restrict__ Cf, u16* __restrict__ Ch,
                                          u16* __restrict__ Cl, int K, int Ncols, int relu) {
    __shared__ u16 AsH[64 * 40], AsL[64 * 40], BsH[64 * 40], BsL[64 * 40];
    int t = threadIdx.x;
    int lane = t & 63, wave = t >> 6;
    int quad = lane >> 4, l16 = lane & 15;
    int wy = wave >> 1, wx = wave & 1;
    int mBase = blockIdx.x * 64, nBase = blockIdx.y * 64;
    f32x4 acc00 = {0.f, 0.f, 0.f, 0.f}, acc01 = acc00, acc10 = acc00, acc11 = acc00;
    int ar = t >> 2, aks = (t & 3) * 8;
    const int nslab = K >> 5;
    const u16* apH = Ah + (size_t)(mBase + ar) * K + aks;
    const u16* apL = Al + (size_t)(mBase + ar) * K + aks;
    us8 rah = *(const us8*)apH;
    us8 ral = *(const us8*)apL;
    us8 rbh = *(const us8*)(Bh + (size_t)nBase * 32 + t * 8);
    us8 rbl = *(const us8*)(Bl + (size_t)nBase * 32 + t * 8);
    for (int s = 0; s < nslab; s++) {
        __syncthreads();
        *(us8*)&AsH[ar * 40 + aks] = rah;
        *(us8*)&AsL[ar * 40 + aks] = ral;
        *(us8*)&BsH[ar * 40 + aks] = rbh;
        *(us8*)&BsL[ar * 40 + aks] = rbl;
        __syncthreads();
        if (s + 1 < nslab) {
            rah = *(const us8*)(apH + (s + 1) * 32);
            ral = *(const us8*)(apL + (s + 1) * 32);
            rbh = *(const us8*)(Bh + ((size_t)(s + 1) * Ncols + nBase) * 32 + t * 8);
            rbl = *(const us8*)(Bl + ((size_t)(s + 1) * Ncols + nBase) * 32 + t * 8);
        }
        bfrag a_h0 = *(const bfrag*)&AsH[(wy * 32 + l16) * 40 + quad * 8];
        bfrag a_h1 = *(const bfrag*)&AsH[(wy * 32 + 16 + l16) * 40 + quad * 8];
        bfrag a_l0 = *(const bfrag*)&AsL[(wy * 32 + l16) * 40 + quad * 8];
        bfrag a_l1 = *(const bfrag*)&AsL[(wy * 32 + 16 + l16) * 40 + quad * 8];
        bfrag b_h0 = *(const bfrag*)&BsH[(wx * 32 + l16) * 40 + quad * 8];
        bfrag b_h1 = *(const bfrag*)&BsH[(wx * 32 + 16 + l16) * 40 + quad * 8];
        bfrag b_l0 = *(const bfrag*)&BsL[(wx * 32 + l16) * 40 + quad * 8];
        bfrag b_l1 = *(const bfrag*)&BsL[(wx * 32 + 16 + l16) * 40 + quad * 8];
        acc00 = __builtin_amdgcn_mfma_f32_16x16x32_bf16(a_h0, b_h0, acc00, 0, 0, 0);
        acc01 = __builtin_amdgcn_mfma_f32_16x16x32_bf16(a_h0, b_h1, acc01, 0, 0, 0);
        acc10 = __builtin_amdgcn_mfma_f32_16x16x32_bf16(a_h1, b_h0, acc10, 0, 0, 0);
        acc11 = __builtin_amdgcn_mfma_f32_16x16x32_bf16(a_h1, b_h1, acc11, 0, 0, 0);
        acc00 = __builtin_amdgcn_mfma_f32_16x16x32_bf16(a_h0, b_l0, acc00, 0, 0, 0);
        acc01 = __builtin_amdgcn_mfma_f32_16x16x32_bf16(a_h0, b_l1, acc01, 0, 0, 0);
        acc10 = __builtin_amdgcn_mfma_f32_16x16x32_bf16(a_h1, b_l0, acc10, 0, 0, 0);
        acc11 = __builtin_amdgcn_mfma_f32_16x16x32_bf16(a_h1, b_l1, acc11, 0, 0, 0);
        acc00 = __builtin_amdgcn_mfma_f32_16x16x32_bf16(a_l0, b_h0, acc00, 0, 0, 0);
        acc01 = __builtin_amdgcn_mfma_f32_16x16x32_bf16(a_l0, b_h1, acc01, 0, 0, 0);
        acc10 = __builtin_amdgcn_mfma_f32_16x16x32_bf16(a_l1, b_h0, acc10, 0, 0, 0);
        acc11 = __builtin_amdgcn_mfma_f32_16x16x32_bf16(a_l1, b_h1, acc11, 0, 0, 0);
    }
    int col0 = nBase + wx * 32 + l16;
    int col1 = col0 + 16;
    float bia0 = bias ? bias[col0] : 0.f;
    float bia1 = bias ? bias[col1] : 0.f;
    #pragma unroll
    for (int r = 0; r < 4; r++) {
        int row0 = mBase + wy * 32 + quad * 4 + r;
        int row1 = row0 + 16;
        float v00 = acc00[r] + bia0, v01 = acc01[r] + bia1;
        float v10 = acc10[r] + bia0, v11 = acc11[r] + bia1;
        if (R) {
            v00 += R[(size_t)row0 * Ncols + col0];
            v01 += R[(size_t)row0 * Ncols + col1];
            v10 += R[(size_t)row1 * Ncols + col0];
            v11 += R[(size_t)row1 * Ncols + col1];
        }
        if (relu) {
            v00 = fmaxf(v00, 0.f); v01 = fmaxf(v01, 0.f);
            v10 = fmaxf(v10, 0.f); v11 = fmaxf(v11, 0.f);
        }
        if (Cf) {
            Cf[(size_t)row0 * Ncols + col0] = v00;
            Cf[(size_t)row0 * Ncols + col1] = v01;
            Cf[(size_t)row1 * Ncols + col0] = v10;
            Cf[(size_t)row1 * Ncols + col1] = v11;
        } else {
            u16 h, l;
            bsplit(v00, h, l); Ch[(size_t)row0 * Ncols + col0] = h; Cl[(size_t)row0 * Ncols + col0] = l;
            bsplit(v01, h, l); Ch[(size_t)row0 * Ncols + col1] = h; Cl[(size_t)row0 * Ncols + col1] = l;
            bsplit(v10, h, l); Ch[(size_t)row1 * Ncols + col0] = h; Cl[(size_t)row1 * Ncols + col0] = l;
            bsplit(v11, h, l); Ch[(size_t)row1 * Ncols + col1] = h; Cl[(size_t)row1 * Ncols + col1] = l;
        }
    }
}

// z = j*3 + which(q/k/v); grid (16,4,6)
__global__ __launch_bounds__(256) void k_qkv(const u16* __restrict__ rowh, const u16* __restrict__ rowl,
                                             const u16* __restrict__ colh, const u16* __restrict__ coll,
                                             const u16* __restrict__ WqTh, const u16* __restrict__ WqTl,
                                             const u16* __restrict__ WkTh, const u16* __restrict__ WkTl,
                                             const u16* __restrict__ WvTh, const u16* __restrict__ WvTl,
                                             int lb2,
                                             float* q0, float* k0, float* v0,
                                             float* q1, float* k1, float* v1) {
    int z = blockIdx.z;
    int j = z / 3, w = z % 3;
    const u16* Ah = (w == 0) ? (j ? colh : rowh) : (j ? rowh : colh);
    const u16* Al = (w == 0) ? (j ? coll : rowl) : (j ? rowl : coll);
    const u16* Wh = (w == 0 ? WqTh : (w == 1 ? WkTh : WvTh)) + (size_t)(lb2 + j) * E * E;
    const u16* Wl = (w == 0 ? WqTl : (w == 1 ? WkTl : WvTl)) + (size_t)(lb2 + j) * E * E;
    float* outs[6] = {q0, k0, v0, q1, k1, v1};
    mfma_gemm(Ah, Al, Wh, Wl, nullptr, nullptr, outs[z], nullptr, nullptr, E, E, 0);
}

__global__ __launch_bounds__(256) void k_mgemm(const u16* Ah0, const u16* Al0,
                                               const u16* Ah1, const u16* Al1,
                                               const u16* __restrict__ Bh, const u16* __restrict__ Bl,
                                               int lb2, long wstride,
                                               const float* __restrict__ biasl, int bstride,
                                               const float* R0, const float* R1,
                                               float* Cf0, float* Cf1,
                                               u16* Ch0, u16* Cl0, u16* Ch1, u16* Cl1,
                                               int K, int Ncols, int relu) {
    int j = blockIdx.z;
    mfma_gemm(j ? Ah1 : Ah0, j ? Al1 : Al0,
              Bh + (size_t)(lb2 + j) * wstride, Bl + (size_t)(lb2 + j) * wstride,
              biasl ? biasl + (size_t)j * bstride : nullptr,
              R0 ? (j ? R1 : R0) : nullptr,
              Cf0 ? (j ? Cf1 : Cf0) : nullptr,
              Ch0 ? (j ? Ch1 : Ch0) : nullptr,
              Cl0 ? (j ? Cl1 : Cl0) : nullptr,
              K, Ncols, relu);
}

// ================= fused attention =================
// grid (B*H=64, 8 n-groups of 32, 2 j), 256 thr; 8 lanes per row; out bf16 hi/lo.
// Per-batch min/max reduced inline from pmin/pmax partials (exact: min/max associative).
__global__ __launch_bounds__(256) void k_attn(const float* __restrict__ q0, const float* __restrict__ k0,
                                              const float* __restrict__ v0, const float* __restrict__ q1,
                                              const float* __restrict__ k1, const float* __restrict__ v1,
                                              const float* __restrict__ data, const float* __restrict__ dataT,
                                              const float* __restrict__ pmin, const float* __restrict__ pmax,
                                              const float* __restrict__ c1c0, int lj_base,
                                              u16* __restrict__ atth0, u16* __restrict__ attl0,
                                              u16* __restrict__ atth1, u16* __restrict__ attl1) {
    int bh = blockIdx.x;
    int b = bh >> 4, h = bh & 15;
    int ng = blockIdx.y;
    int j = blockIdx.z;
    const float* q = j ? q1 : q0;
    const float* k = j ? k1 : k0;
    const float* v = j ? v1 : v0;
    float mn = 1e30f, mx = -1e30f;
    #pragma unroll
    for (int p = 0; p < 16; p++) {
        mn = fminf(mn, pmin[b * 16 + p]);
        mx = fmaxf(mx, pmax[b * 16 + p]);
    }
    float rng = mx - mn;
    if (rng == 0.f) rng = 1.f;
    float inv = 1.f / rng;
    float c1 = c1c0[(lj_base + j) * 16 + h];
    float c0 = c1c0[160 + (lj_base + j) * 16 + h];
    float c1p = inv * c1;
    float c0p = c0 - mn * c1p;

    __shared__ float kl[256 * 20];
    __shared__ float vl[256 * 20];
    int t = threadIdx.x;
    {
        int c = t & 3, mb = t >> 2;
        #pragma unroll
        for (int it = 0; it < 4; it++) {
            int m = mb + 64 * it;
            const float* kp = k + ((size_t)(b * NN + m) * E) + h * DD + c * 4;
            const float* vp = v + ((size_t)(b * NN + m) * E) + h * DD + c * 4;
            *(float4*)&kl[m * 20 + c * 4] = *(const float4*)kp;
            *(float4*)&vl[m * 20 + c * 4] = *(const float4*)vp;
        }
    }
    __syncthreads();

    int lane = t & 63, w = t >> 6;
    int r = lane >> 3, ml = lane & 7;
    int n = ng * 32 + w * 8 + r;

    float qr[16];
    const float* qp = q + ((size_t)(b * NN + n) * E) + h * DD;
    #pragma unroll
    for (int d4 = 0; d4 < 4; d4++) {
        float4 q4 = *(const float4*)(qp + d4 * 4);
        qr[d4 * 4 + 0] = q4.x; qr[d4 * 4 + 1] = q4.y;
        qr[d4 * 4 + 2] = q4.z; qr[d4 * 4 + 3] = q4.w;
    }
    const float* pedge = (j ? dataT : data) + (size_t)b * NN * NN + (size_t)n * NN;

    float sum = 0.f;
    float acc[16] = {};
    for (int i = 0; i < 32; i++) {
        int m = ml + 8 * i;
        float4 ka = *(const float4*)&kl[m * 20 + 0];
        float4 kb = *(const float4*)&kl[m * 20 + 4];
        float4 kc = *(const float4*)&kl[m * 20 + 8];
        float4 kd = *(const float4*)&kl[m * 20 + 12];
        float s0 = qr[0] * ka.x + qr[1] * ka.y + qr[2] * ka.z + qr[3] * ka.w;
        float s1 = qr[4] * kb.x + qr[5] * kb.y + qr[6] * kb.z + qr[7] * kb.w;
        float s2 = qr[8] * kc.x + qr[9] * kc.y + qr[10] * kc.z + qr[11] * kc.w;
        float s3 = qr[12] * kd.x + qr[13] * kd.y + qr[14] * kd.z + qr[15] * kd.w;
        float s = ((s0 + s1) + (s2 + s3)) * 0.25f + pedge[m] * c1p + c0p;
        float e = __expf(s);
        sum += e;
        float4 va = *(const float4*)&vl[m * 20 + 0];
        float4 vb = *(const float4*)&vl[m * 20 + 4];
        float4 vc = *(const float4*)&vl[m * 20 + 8];
        float4 vd = *(const float4*)&vl[m * 20 + 12];
        acc[0] += e * va.x;  acc[1] += e * va.y;  acc[2] += e * va.z;  acc[3] += e * va.w;
        acc[4] += e * vb.x;  acc[5] += e * vb.y;  acc[6] += e * vb.z;  acc[7] += e * vb.w;
        acc[8] += e * vc.x;  acc[9] += e * vc.y;  acc[10] += e * vc.z; acc[11] += e * vc.w;
        acc[12] += e * vd.x; acc[13] += e * vd.y; acc[14] += e * vd.z; acc[15] += e * vd.w;
    }
    #pragma unroll
    for (int mask = 1; mask <= 4; mask <<= 1) {
        sum += __shfl_xor(sum, mask);
        #pragma unroll
        for (int d = 0; d < 16; d++) acc[d] += __shfl_xor(acc[d], mask);
    }
    if (ml == 0) {
        float invs = 1.f / sum;
        u16 hh[16], ll[16];
        #pragma unroll
        for (int d = 0; d < 16; d++) bsplit(acc[d] * invs, hh[d], ll[d]);
        size_t base = ((size_t)(b * NN + n) * E) + h * DD;
        u16* oh = (j ? atth1 : atth0) + base;
        u16* ol = (j ? attl1 : attl0) + base;
        *(us8*)oh = *(const us8*)&hh[0];
        *(us8*)(oh + 8) = *(const us8*)&hh[8];
        *(us8*)ol = *(const us8*)&ll[0];
        *(us8*)(ol + 8) = *(const us8*)&ll[8];
    }
}

// ================= instance norm over node dim =================
// grid (B, 2 j, 32 e-chunks of 8), 256 thr; fp32 + bf16 hi/lo outputs.
__global__ __launch_bounds__(256) void k_inorm(const float* __restrict__ Y0, const float* __restrict__ Y1,
                                               const float* __restrict__ wl, const float* __restrict__ bl,
                                               int pstride,
                                               float* Of0, float* Of1,
                                               u16* Oh0, u16* Ol0, u16* Oh1, u16* Ol1,
                                               float* __restrict__ fout) {
    int b = blockIdx.x, j = blockIdx.y;
    int ec = blockIdx.z * 8;
    const float* Y = (j ? Y1 : Y0) + (size_t)b * NN * E;
    float* O = (j ? Of1 : Of0) + (size_t)b * NN * E;
    u16* Oh = (j ? Oh1 : Oh0) + (size_t)b * NN * E;
    u16* Ol = (j ? Ol1 : Ol0) + (size_t)b * NN * E;
    const float* w = wl + (size_t)j * pstride;
    const float* bb = bl + (size_t)j * pstride;
    int t = threadIdx.x;
    int et = t & 7, n0 = t >> 3;
    int e = ec + et;
    float vals[8];
    float s = 0.f, s2 = 0.f;
    #pragma unroll
    for (int kk = 0; kk < 8; kk++) {
        float v = Y[(size_t)(n0 + 32 * kk) * E + e];
        vals[kk] = v;
        s += v;
        s2 += v * v;
    }
    __shared__ float ps[32 * 9], ps2[32 * 9];
    ps[n0 * 9 + et] = s;
    ps2[n0 * 9 + et] = s2;
    __syncthreads();
    float st = 0.f, st2 = 0.f;
    #pragma unroll
    for (int kk = 0; kk < 32; kk++) { st += ps[kk * 9 + et]; st2 += ps2[kk * 9 + et]; }
    float mu = st * (1.f / NN);
    float var = fmaxf(st2 * (1.f / NN) - mu * mu, 0.f);
    float scale = w[e] * rsqrtf(var + 1e-5f);
    float shift = bb[e] - mu * scale;
    #pragma unroll
    for (int kk = 0; kk < 8; kk++) {
        float vv = vals[kk] * scale + shift;
        size_t idx = (size_t)(n0 + 32 * kk) * E + e;
        O[idx] = vv;
        u16 hh, ll;
        bsplit(vv, hh, ll);
        Oh[idx] = hh;
        Ol[idx] = ll;
        if (fout) fout[(size_t)j * (BB * NN * E) + (size_t)b * NN * E + idx] = vv;
    }
}

// ---------------- host ----------------

extern "C" void kernel_launch(void* const* d_in, const int* in_sizes, int n_in,
                              void* d_out, int out_size, void* d_ws, size_t ws_size,
                              hipStream_t stream) {
    const float* data      = (const float*)d_in[0];
    const float* node_rand = (const float*)d_in[1];
    const float* Wnode     = (const float*)d_in[2];
    const float* bnode     = (const float*)d_in[3];
    const float* Wedge     = (const float*)d_in[4];
    const float* bedge     = (const float*)d_in[5];
    const float* Wq        = (const float*)d_in[6];
    const float* Wk        = (const float*)d_in[7];
    const float* Wv        = (const float*)d_in[8];
    const float* Wcomb     = (const float*)d_in[9];
    const float* bcomb     = (const float*)d_in[10];
    const float* n1w       = (const float*)d_in[11];
    const float* n1b       = (const float*)d_in[12];
    const float* W1        = (const float*)d_in[13];
    const float* b1        = (const float*)d_in[14];
    const float* W2        = (const float*)d_in[15];
    const float* b2        = (const float*)d_in[16];
    const float* n2w       = (const float*)d_in[17];
    const float* n2b       = (const float*)d_in[18];
    const float* Wmix      = (const float*)d_in[19];
    float* out = (float*)d_out;  // (row, col) concat

    float* ws = (float*)d_ws;
    const size_t T = (size_t)MROWS * E;      // 262144
    const size_t TF = (size_t)MROWS * FFH;   // 524288
    float* dataT = ws + 0 * T;
    float* row   = ws + 1 * T;
    float* col   = ws + 2 * T;
    float* q0    = ws + 3 * T;
    float* q1    = ws + 4 * T;
    float* k0    = ws + 5 * T;
    float* k1    = ws + 6 * T;
    float* v0    = ws + 7 * T;
    float* v1    = ws + 8 * T;
    float* o1f0  = ws + 9 * T;
    float* o1f1  = ws + 10 * T;
    float* pmin  = ws + 11 * T;
    float* pmax  = pmin + 64;
    float* c1c0  = pmax + 64;
    u16* us = (u16*)(ws + 11 * T + 512);
    auto nxt = [&](size_t n) { u16* p = us; us += n; return p; };
    u16* rowh = nxt(T);  u16* rowl = nxt(T);
    u16* colh = nxt(T);  u16* coll = nxt(T);
    u16* atth0 = nxt(T); u16* attl0 = nxt(T);
    u16* atth1 = nxt(T); u16* attl1 = nxt(T);
    u16* o1h0 = nxt(T);  u16* o1l0 = nxt(T);
    u16* o1h1 = nxt(T);  u16* o1l1 = nxt(T);
    u16* ffhh0 = nxt(TF); u16* ffhl0 = nxt(TF);
    u16* ffhh1 = nxt(TF); u16* ffhl1 = nxt(TF);
    const size_t EE10 = (size_t)10 * E * E;
    const size_t EF10 = (size_t)10 * E * FFH;
    u16* WqTh = nxt(EE10); u16* WqTl = nxt(EE10);
    u16* WkTh = nxt(EE10); u16* WkTl = nxt(EE10);
    u16* WvTh = nxt(EE10); u16* WvTl = nxt(EE10);
    u16* WcTh = nxt(EE10); u16* WcTl = nxt(EE10);
    u16* W1Th = nxt(EF10); u16* W1Tl = nxt(EF10);
    u16* W2Th = nxt(EF10); u16* W2Tl = nxt(EF10);
    // fp32 aliases (liveness-checked, identical to the 461us version)
    float* y0 = q0;   float* y1 = q1;     // comb out (q dead after attn)
    float* y20 = q0;  float* y21 = q1;    // FF2 out (y dead after IN1)

    k_prep<<<3905, 256, 0, stream>>>(data, node_rand, Wnode, bnode,
                                     Wedge, bedge, Wmix,
                                     Wq, Wk, Wv, Wcomb, W1, W2,
                                     pmin, pmax, c1c0,
                                     row, col, rowh, rowl, colh, coll, dataT,
                                     WqTh, WqTl, WkTh, WkTl, WvTh, WvTl,
                                     WcTh, WcTl, W1Th, W1Tl, W2Th, W2Tl);

    for (int l = 0; l < LAYERS; l++) {
        int lb2 = l * 2;
        k_qkv<<<dim3(16, 4, 6), 256, 0, stream>>>(rowh, rowl, colh, coll,
                                                  WqTh, WqTl, WkTh, WkTl, WvTh, WvTl, lb2,
                                                  q0, k0, v0, q1, k1, v1);
        k_attn<<<dim3(64, 8, 2), 256, 0, stream>>>(q0, k0, v0, q1, k1, v1, data, dataT,
                                                   pmin, pmax, c1c0, lb2,
                                                   atth0, attl0, atth1, attl1);
        k_mgemm<<<dim3(16, 4, 2), 256, 0, stream>>>(atth0, attl0, atth1, attl1,
                                                    WcTh, WcTl, lb2, (long)E * E,
                                                    bcomb, E,
                                                    row, col, y0, y1,
                                                    nullptr, nullptr, nullptr, nullptr,
                                                    E, E, 0);
        k_inorm<<<dim3(BB, 2, 32), 256, 0, stream>>>(y0, y1,
                                                     n1w + (size_t)lb2 * E, n1b + (size_t)lb2 * E, E,
                                                     o1f0, o1f1, o1h0, o1l0, o1h1, o1l1, nullptr);
        k_mgemm<<<dim3(16, 8, 2), 256, 0, stream>>>(o1h0, o1l0, o1h1, o1l1,
                                                    W1Th, W1Tl, lb2, (long)E * FFH,
                                                    b1, FFH,
                                                    nullptr, nullptr, nullptr, nullptr,
                                                    ffhh0, ffhl0, ffhh1, ffhl1,
                                                    E, FFH, 1);
        k_mgemm<<<dim3(16, 4, 2), 256, 0, stream>>>(ffhh0, ffhl0, ffhh1, ffhl1,
                                                    W2Th, W2Tl, lb2, (long)FFH * E,
                                                    b2, E,
                                                    o1f0, o1f1, q0 /*y20*/, q1 /*y21*/,
                                                    nullptr, nullptr, nullptr, nullptr,
                                                    FFH, E, 0);
        k_inorm<<<dim3(BB, 2, 32), 256, 0, stream>>>(y20, y21,
                                                     n2w + (size_t)lb2 * E, n2b + (size_t)lb2 * E, E,
                                                     row, col, rowh, rowl, colh, coll,
                                                     (l == LAYERS - 1) ? out : nullptr);
    }
}